// Round 9
// baseline (487.440 us; speedup 1.0000x reference)
//
#include <hip/hip_runtime.h>
#include <stdint.h>

#define NN 50000
#define EE 1600000
#define IN_DIMC 256
#define HIDC 128
#define EPSC 1e-5f

// counting-sort geometry
#define NB 196        // coarse buckets: dst>>8, 256 nodes/bucket (196*256 >= 50000)
#define GA 512        // phase-A blocks
#define CHUNK 3125    // EE / GA exactly
#define STILE_SHIFT 13   // src tile = src>>13 -> 7 tiles over 50000 nodes
#define NKEY 2048        // fine keys: (dst&255)<<3 | srctile

#define NSLOT 8          // stats atomic slots (contention /8)
#define STATS_STRIDE (NSLOT * 256)   // floats per stage

typedef unsigned short ushort_t;
typedef __attribute__((ext_vector_type(8))) short short8;
typedef __attribute__((ext_vector_type(4))) float floatx4;

static __device__ inline ushort_t f2bf(float f) {
    unsigned int u = __float_as_uint(f);
    u = u + 0x7fffu + ((u >> 16) & 1u);   // RNE
    return (ushort_t)(u >> 16);
}
static __device__ inline unsigned int pack2(float a, float b) {
    return (unsigned int)f2bf(a) | ((unsigned int)f2bf(b) << 16);
}
static __device__ inline float bf2f(unsigned int bits16) {
    return __uint_as_float(bits16 << 16);
}

// ---------------------------------------------------------------------------
// All six weight transposes + bf16 convert in ONE launch.
// ---------------------------------------------------------------------------
__global__ __launch_bounds__(256) void tcvt_all_kernel(
    const float* __restrict__ W_in, const float* __restrict__ W_hid,
    const float* __restrict__ Wl1, const float* __restrict__ Wr1,
    const float* __restrict__ Wl2, const float* __restrict__ Wr2,
    ushort_t* __restrict__ Wt_in, ushort_t* __restrict__ Wt_hid,
    ushort_t* __restrict__ Wtl1, ushort_t* __restrict__ Wtr1,
    ushort_t* __restrict__ Wtl2, ushort_t* __restrict__ Wtr2)
{
    const int idx = blockIdx.x * 256 + threadIdx.x;
    if (idx < 32768) {
        const int n = idx >> 8;           // /256
        const int k = idx & 255;
        Wt_in[idx] = f2bf(W_in[(size_t)k * 128 + n]);
    } else if (idx < 32768 + 5 * 16384) {
        const int r = idx - 32768;
        const int seg = r / 16384;
        const int j = r - seg * 16384;
        const int n = j >> 7;
        const int k = j & 127;
        const float* W; ushort_t* Wt;
        switch (seg) {
            case 0: W = W_hid; Wt = Wt_hid; break;
            case 1: W = Wl1;  Wt = Wtl1;  break;
            case 2: W = Wr1;  Wt = Wtr1;  break;
            case 3: W = Wl2;  Wt = Wtl2;  break;
            default: W = Wr2; Wt = Wtr2;  break;
        }
        Wt[j] = f2bf(W[(size_t)k * 128 + n]);
    }
}

// ---------------------------------------------------------------------------
// MFMA GEMM v5.3: v5.1 body (no A-hoist) + __launch_bounds__(512,8) pinning
// VGPR <= 64 so 32 waves/CU are resident (round-8's hoist hit 72 VGPR ->
// waves/CU halved to 16 -> occupancy 17%, -10us/launch).
// 512-thread blocks (8 waves), 64 rows/block, wave-tile 16 rows x 64 cols.
// B panel (128xK-chunk) staged once into LDS shared by 8 waves.
// A fragments per lane: row = lane&15, k = ks*32 + (lane>>4)*8 (verified).
// affineSeg: -1 none, 0/1 = apply BN affine (+optional relu) on that A's load.
// preStats/outStats are NSLOT-slotted (slot = blockIdx & 7).
// ---------------------------------------------------------------------------
__global__ __launch_bounds__(512, 8) void mfma_gemm_kernel(
    const void* __restrict__ A1, const ushort_t* __restrict__ Wt1, int K1, int a1type,
    const void* __restrict__ A2, const ushort_t* __restrict__ Wt2, int K2,
    const float* __restrict__ bias, float* __restrict__ Cf, ushort_t* __restrict__ Cb,
    int M, int affineSeg, int affineRelu,
    const float* __restrict__ preStats, const float* __restrict__ preG,
    const float* __restrict__ preBe, float* __restrict__ outStats)
{
    __shared__ ushort_t Bs[128 * 136];                 // 34816 B
    __shared__ __align__(16) float aArr[128], bArr[128];
    __shared__ float red_s[4][128], red_q[4][128];

    const int t    = threadIdx.x;          // 0..511
    const int lane = t & 63;
    const int wave = t >> 6;               // 0..7
    const int mt   = wave >> 1;            // 0..3 row sub-tile
    const int nh   = wave & 1;             // col half
    const int quad = lane >> 4;
    const int l15  = lane & 15;
    const int row0 = blockIdx.x * 64;
    const int rowW = row0 + mt * 16;       // wave's 16 rows
    const int ksq  = quad * 8;

    if (affineSeg >= 0 && t < 128) {
        float sS = 0.0f, sQ = 0.0f;
        #pragma unroll
        for (int s8 = 0; s8 < NSLOT; s8++) {
            sS += preStats[s8 * 256 + t];
            sQ += preStats[s8 * 256 + 128 + t];
        }
        const float invM = 1.0f / (float)M;
        const float mean = sS * invM;
        float var = sQ * invM - mean * mean;
        if (var < 0.0f) var = 0.0f;
        const float s = preG[t] / sqrtf(var + EPSC);
        aArr[t] = s;
        bArr[t] = preBe[t] - mean * s;
    }
    // aArr/bArr consumed only after the first staging __syncthreads()

    floatx4 acc[4];
    #pragma unroll
    for (int j = 0; j < 4; j++)
        acc[j] = (floatx4){0.0f, 0.0f, 0.0f, 0.0f};

    int gr = rowW + l15;
    if (gr > M - 1) gr = M - 1;

    bool firstChunk = true;

    for (int s = 0; s < 2; s++) {
        const void*     A     = s ? A2  : A1;
        const ushort_t* Wt    = s ? Wt2 : Wt1;
        const int       K     = s ? K2  : K1;
        const int       atype = s ? 1   : a1type;
        const int       doAf  = (affineSeg == s);
        if (A == nullptr) continue;

        for (int kc = 0; kc < K; kc += 128) {
            if (!firstChunk) __syncthreads();   // protect Bs until prior compute done
            firstChunk = false;

            // ---- stage B panel: 128 rows x 128 K bf16 (32 KB), 4 uint4/thread ----
            #pragma unroll
            for (int p = 0; p < 4; p++) {
                const int idx = p * 512 + t;    // 0..2047
                const int n   = idx >> 4;
                const int c0  = (idx & 15) * 8;
                *(uint4*)(Bs + n * 136 + c0) =
                    *(const uint4*)(Wt + (size_t)n * K + kc + c0);
            }
            __syncthreads();

            // ---- A fragments: 4 k-steps, per-lane, direct global->VGPR ----
            short8 afrag[4];
            if (atype == 1) {
                const ushort_t* Ab = (const ushort_t*)A;
                const size_t base = (size_t)gr * K + kc + ksq;
                #pragma unroll
                for (int ks = 0; ks < 4; ks++)
                    afrag[ks] = *(const short8*)(Ab + base + ks * 32);
                if (doAf) {
                    #pragma unroll
                    for (int ks = 0; ks < 4; ks++) {
                        const int k0 = ks * 32 + ksq;   // K==128 when affine
                        uint4 u = __builtin_bit_cast(uint4, afrag[ks]);
                        uint4 w;
                        unsigned int* up = (unsigned int*)&u;
                        unsigned int* wp = (unsigned int*)&w;
                        #pragma unroll
                        for (int h = 0; h < 4; h++) {
                            float lo = aArr[k0 + h * 2]     * bf2f(up[h] & 0xffffu) + bArr[k0 + h * 2];
                            float hi = aArr[k0 + h * 2 + 1] * bf2f(up[h] >> 16)     + bArr[k0 + h * 2 + 1];
                            if (affineRelu) { lo = fmaxf(lo, 0.0f); hi = fmaxf(hi, 0.0f); }
                            wp[h] = pack2(lo, hi);
                        }
                        afrag[ks] = __builtin_bit_cast(short8, w);
                    }
                }
            } else {
                const float* Af = (const float*)A;
                const size_t base = (size_t)gr * K + kc + ksq;
                #pragma unroll
                for (int ks = 0; ks < 4; ks++) {
                    float4 v0 = *(const float4*)(Af + base + ks * 32);
                    float4 v1 = *(const float4*)(Af + base + ks * 32 + 4);
                    if (doAf) {
                        const int k0 = ks * 32 + ksq;
                        const float4 sa0 = *(const float4*)(aArr + k0);
                        const float4 sb0 = *(const float4*)(bArr + k0);
                        const float4 sa1 = *(const float4*)(aArr + k0 + 4);
                        const float4 sb1 = *(const float4*)(bArr + k0 + 4);
                        v0.x = sa0.x * v0.x + sb0.x;
                        v0.y = sa0.y * v0.y + sb0.y;
                        v0.z = sa0.z * v0.z + sb0.z;
                        v0.w = sa0.w * v0.w + sb0.w;
                        v1.x = sa1.x * v1.x + sb1.x;
                        v1.y = sa1.y * v1.y + sb1.y;
                        v1.z = sa1.z * v1.z + sb1.z;
                        v1.w = sa1.w * v1.w + sb1.w;
                        if (affineRelu) {
                            v0.x = fmaxf(v0.x, 0.0f); v0.y = fmaxf(v0.y, 0.0f);
                            v0.z = fmaxf(v0.z, 0.0f); v0.w = fmaxf(v0.w, 0.0f);
                            v1.x = fmaxf(v1.x, 0.0f); v1.y = fmaxf(v1.y, 0.0f);
                            v1.z = fmaxf(v1.z, 0.0f); v1.w = fmaxf(v1.w, 0.0f);
                        }
                    }
                    uint4 w;
                    w.x = pack2(v0.x, v0.y);
                    w.y = pack2(v0.z, v0.w);
                    w.z = pack2(v1.x, v1.y);
                    w.w = pack2(v1.z, v1.w);
                    afrag[ks] = __builtin_bit_cast(short8, w);
                }
            }

            // ---- compute: wave's 64 cols (nh half), ks outer ----
            #pragma unroll
            for (int ks = 0; ks < 4; ks++) {
                const int ko = ks * 32 + ksq;
                short8 b[4];
                #pragma unroll
                for (int j = 0; j < 4; j++)
                    b[j] = *(const short8*)(Bs + (nh * 64 + j * 16 + l15) * 136 + ko);
                #pragma unroll
                for (int j = 0; j < 4; j++)
                    acc[j] = __builtin_amdgcn_mfma_f32_16x16x32_bf16(
                        afrag[ks], b[j], acc[j], 0, 0, 0);
            }
        }
    }

    // ---- epilogue: bias, C store (fp32 and/or bf16), per-column stats ----
    float s_[4], q_[4];
    #pragma unroll
    for (int j = 0; j < 4; j++) { s_[j] = 0.0f; q_[j] = 0.0f; }

    #pragma unroll
    for (int j = 0; j < 4; j++) {
        const int col = nh * 64 + j * 16 + l15;
        const float bv = bias[col];
        const int rbase = rowW + quad * 4;
        #pragma unroll
        for (int reg = 0; reg < 4; reg++) {
            const float val = acc[j][reg] + bv;
            const int r_ = rbase + reg;
            if (r_ < M) {
                if (Cf) Cf[(size_t)r_ * HIDC + col] = val;
                if (Cb) Cb[(size_t)r_ * HIDC + col] = f2bf(val);
                s_[j] += val;
                q_[j] += val * val;
            }
        }
    }
    #pragma unroll
    for (int j = 0; j < 4; j++) {
        s_[j] += __shfl_xor(s_[j], 16, 64);
        s_[j] += __shfl_xor(s_[j], 32, 64);
        q_[j] += __shfl_xor(q_[j], 16, 64);
        q_[j] += __shfl_xor(q_[j], 32, 64);
    }
    if (quad == 0) {
        #pragma unroll
        for (int j = 0; j < 4; j++) {
            red_s[mt][nh * 64 + j * 16 + l15] = s_[j];
            red_q[mt][nh * 64 + j * 16 + l15] = q_[j];
        }
    }
    __syncthreads();
    if (t < 128) {
        const float S = red_s[0][t] + red_s[1][t] + red_s[2][t] + red_s[3][t];
        const float Q = red_q[0][t] + red_q[1][t] + red_q[2][t] + red_q[3][t];
        float* slot = outStats + (blockIdx.x & (NSLOT - 1)) * 256;
        atomicAdd(&slot[t], S);
        atomicAdd(&slot[128 + t], Q);
    }
}

// ---------------------------------------------------------------------------
// BN apply: dst fp32 (optional) and/or dst bf16 (optional), + optional relu.
// stats is NSLOT-slotted.
// ---------------------------------------------------------------------------
__global__ __launch_bounds__(256) void bn_apply_kernel(
    const float* __restrict__ src, float* __restrict__ dstF,
    ushort_t* __restrict__ dstB, const float* __restrict__ stats,
    const float* __restrict__ gamma, const float* __restrict__ beta,
    int relu, int M)
{
    __shared__ float sc[128], sh[128];
    const int t = threadIdx.x;
    if (t < 128) {
        float sS = 0.0f, sQ = 0.0f;
        #pragma unroll
        for (int s8 = 0; s8 < NSLOT; s8++) {
            sS += stats[s8 * 256 + t];
            sQ += stats[s8 * 256 + 128 + t];
        }
        const float invM = 1.0f / (float)M;
        const float mean = sS * invM;
        float var = sQ * invM - mean * mean;
        if (var < 0.0f) var = 0.0f;
        const float s = gamma[t] / sqrtf(var + EPSC);
        sc[t] = s;
        sh[t] = beta[t] - mean * s;
    }
    __syncthreads();

    const int total4 = M * HIDC / 4;
    for (int i = blockIdx.x * 256 + t; i < total4; i += gridDim.x * 256) {
        float4 v = ((const float4*)src)[i];
        const int c = (i * 4) & 127;
        v.x = v.x * sc[c]     + sh[c];
        v.y = v.y * sc[c + 1] + sh[c + 1];
        v.z = v.z * sc[c + 2] + sh[c + 2];
        v.w = v.w * sc[c + 3] + sh[c + 3];
        if (relu) {
            v.x = fmaxf(v.x, 0.0f); v.y = fmaxf(v.y, 0.0f);
            v.z = fmaxf(v.z, 0.0f); v.w = fmaxf(v.w, 0.0f);
        }
        if (dstF) ((float4*)dstF)[i] = v;
        if (dstB) {
            uint2 w;
            w.x = pack2(v.x, v.y);
            w.y = pack2(v.z, v.w);
            *(uint2*)(dstB + (size_t)i * 4) = w;
        }
    }
}

// ---------------------------------------------------------------------------
// CSR build — atomic-free two-level counting sort. Edges packed 32-bit
// (src<<16 | dst). Fine phase orders by (dst&255, srctile). col is INT.
// ---------------------------------------------------------------------------
__global__ __launch_bounds__(256) void bucket_hist_kernel(
    const int* __restrict__ dstArr, int* __restrict__ hist2D)
{
    __shared__ int hist[NB];
    const int t = threadIdx.x;
    for (int i = t; i < NB; i += 256) hist[i] = 0;
    __syncthreads();
    const int e0 = blockIdx.x * CHUNK;
    const int e1 = e0 + CHUNK;   // EE = GA*CHUNK exactly
    for (int e = e0 + t; e < e1; e += 256)
        atomicAdd(&hist[dstArr[e] >> 8], 1);
    __syncthreads();
    for (int i = t; i < NB; i += 256)
        hist2D[(size_t)i * GA + blockIdx.x] = hist[i];
}

// per-bucket exclusive scan over the GA=512 phase-A block counts.
__global__ __launch_bounds__(256) void bucket_scan_kernel(
    int* __restrict__ hist2D, int* __restrict__ rowTot)
{
    __shared__ int wtot[4];
    const int b = blockIdx.x;
    const int t = threadIdx.x;
    int* row = hist2D + (size_t)b * GA;
    const int v0 = row[2 * t];
    const int v1 = row[2 * t + 1];
    const int pair = v0 + v1;
    const int lane = t & 63, w = t >> 6;
    int x = pair;
    #pragma unroll
    for (int off = 1; off < 64; off <<= 1) {
        const int y = __shfl_up(x, off);
        if (lane >= off) x += y;
    }
    if (lane == 63) wtot[w] = x;
    __syncthreads();
    int woff = 0;
    #pragma unroll
    for (int j = 0; j < 4; j++) if (j < w) woff += wtot[j];
    const int excl = x + woff - pair;
    row[2 * t]     = excl;
    row[2 * t + 1] = excl + v0;
    if (t == 255) rowTot[b] = excl + pair;
}

// 1 block: exclusive scan of NB bucket totals -> bucketBase.
__global__ __launch_bounds__(256) void bucket_base_kernel(
    const int* __restrict__ rowTot, int* __restrict__ bucketBase,
    int* __restrict__ rowp)
{
    __shared__ int wtot[4];
    const int t = threadIdx.x;
    const int tot = (t < NB) ? rowTot[t] : 0;
    const int lane = t & 63, w = t >> 6;
    int x = tot;
    #pragma unroll
    for (int off = 1; off < 64; off <<= 1) {
        const int y = __shfl_up(x, off);
        if (lane >= off) x += y;
    }
    if (lane == 63) wtot[w] = x;
    __syncthreads();
    int woff = 0;
    #pragma unroll
    for (int j = 0; j < 4; j++) if (j < w) woff += wtot[j];
    const int excl = x + woff - tot;
    if (t < NB) bucketBase[t] = excl;
    if (t == 0) { bucketBase[NB] = EE; rowp[NN] = EE; }
}

__global__ __launch_bounds__(256) void bucket_scatter_kernel(
    const int* __restrict__ srcArr, const int* __restrict__ dstArr,
    const int* __restrict__ hist2D, const int* __restrict__ bucketBase,
    unsigned int* __restrict__ ebuf)
{
    __shared__ int cur[NB];
    const int t = threadIdx.x;
    for (int i = t; i < NB; i += 256)
        cur[i] = bucketBase[i] + hist2D[(size_t)i * GA + blockIdx.x];
    __syncthreads();
    const int e0 = blockIdx.x * CHUNK;
    const int e1 = e0 + CHUNK;
    for (int e = e0 + t; e < e1; e += 256) {
        const int d = dstArr[e];
        const int s = srcArr[e];
        const int p = atomicAdd(&cur[d >> 8], 1);
        ebuf[p] = ((unsigned int)s << 16) | (unsigned int)d;
    }
}

__global__ __launch_bounds__(256) void fine_sort_kernel(
    const unsigned int* __restrict__ ebuf, const int* __restrict__ bucketBase,
    int* __restrict__ rowp, int* __restrict__ col)
{
    __shared__ int cnt[NKEY];       // 8 KB: (dst&255)<<3 | srctile
    __shared__ int wtot[4];
    const int b = blockIdx.x;
    const int t = threadIdx.x;
    const int bb0 = bucketBase[b];
    const int bb1 = bucketBase[b + 1];
    #pragma unroll
    for (int i = 0; i < 8; i++) cnt[t * 8 + i] = 0;
    __syncthreads();
    for (int e = bb0 + t; e < bb1; e += 256) {
        const unsigned int sd = ebuf[e];
        const int key = (int)((sd & 255u) << 3) | (int)(sd >> (16 + STILE_SHIFT));
        atomicAdd(&cnt[key], 1);
    }
    __syncthreads();
    int loc[8];
    int tot = 0;
    #pragma unroll
    for (int i = 0; i < 8; i++) { loc[i] = tot; tot += cnt[t * 8 + i]; }
    const int lane = t & 63, w = t >> 6;
    int x = tot;
    #pragma unroll
    for (int off = 1; off < 64; off <<= 1) {
        const int y = __shfl_up(x, off);
        if (lane >= off) x += y;
    }
    if (lane == 63) wtot[w] = x;
    __syncthreads();
    int woff = 0;
    #pragma unroll
    for (int j = 0; j < 4; j++) if (j < w) woff += wtot[j];
    const int excl = x + woff - tot;
    const int node = b * 256 + t;
    if (node < NN) rowp[node] = bb0 + excl;
    __syncthreads();
    #pragma unroll
    for (int i = 0; i < 8; i++) cnt[t * 8 + i] = excl + loc[i];  // cursors
    __syncthreads();
    for (int e = bb0 + t; e < bb1; e += 256) {
        const unsigned int sd = ebuf[e];
        const int key = (int)((sd & 255u) << 3) | (int)(sd >> (16 + STILE_SHIFT));
        const int p = atomicAdd(&cnt[key], 1);
        col[bb0 + p] = (int)(sd >> 16);
    }
}

// ---------------------------------------------------------------------------
// Mean aggregation (plain): one wave per node, 2 cols/lane, grid-stride over
// 16384 waves — round-1's empirically-best shape, zero affine overhead.
// ---------------------------------------------------------------------------
__global__ __launch_bounds__(256) void agg_kernel(
    const ushort_t* __restrict__ F, const int* __restrict__ row_ptr,
    const int* __restrict__ col, ushort_t* __restrict__ Mout)
{
    const int lane = threadIdx.x & 63;
    const int wave = blockIdx.x * 4 + (threadIdx.x >> 6);
    const int nwaves = gridDim.x * 4;
    const int coff = lane * 2;

    for (int n = wave; n < NN; n += nwaves) {
        const int b = __builtin_amdgcn_readfirstlane(row_ptr[n]);
        const int e = __builtin_amdgcn_readfirstlane(row_ptr[n + 1]);
        const int deg = e - b;
        float accx = 0.0f, accy = 0.0f;
        int j = b;
        for (; j + 8 <= e; j += 8) {
            const int s0 = col[j + 0];
            const int s1 = col[j + 1];
            const int s2 = col[j + 2];
            const int s3 = col[j + 3];
            const int s4 = col[j + 4];
            const int s5 = col[j + 5];
            const int s6 = col[j + 6];
            const int s7 = col[j + 7];
            const unsigned int v0 = *(const unsigned int*)(F + (size_t)s0 * HIDC + coff);
            const unsigned int v1 = *(const unsigned int*)(F + (size_t)s1 * HIDC + coff);
            const unsigned int v2 = *(const unsigned int*)(F + (size_t)s2 * HIDC + coff);
            const unsigned int v3 = *(const unsigned int*)(F + (size_t)s3 * HIDC + coff);
            const unsigned int v4 = *(const unsigned int*)(F + (size_t)s4 * HIDC + coff);
            const unsigned int v5 = *(const unsigned int*)(F + (size_t)s5 * HIDC + coff);
            const unsigned int v6 = *(const unsigned int*)(F + (size_t)s6 * HIDC + coff);
            const unsigned int v7 = *(const unsigned int*)(F + (size_t)s7 * HIDC + coff);
            accx += bf2f(v0 & 0xffffu) + bf2f(v1 & 0xffffu) + bf2f(v2 & 0xffffu)
                  + bf2f(v3 & 0xffffu) + bf2f(v4 & 0xffffu) + bf2f(v5 & 0xffffu)
                  + bf2f(v6 & 0xffffu) + bf2f(v7 & 0xffffu);
            accy += bf2f(v0 >> 16) + bf2f(v1 >> 16) + bf2f(v2 >> 16)
                  + bf2f(v3 >> 16) + bf2f(v4 >> 16) + bf2f(v5 >> 16)
                  + bf2f(v6 >> 16) + bf2f(v7 >> 16);
        }
        for (; j < e; j++) {
            const unsigned int v = *(const unsigned int*)(F + (size_t)col[j] * HIDC + coff);
            accx += bf2f(v & 0xffffu);
            accy += bf2f(v >> 16);
        }
        const float inv = 1.0f / (float)(deg > 1 ? deg : 1);
        *(unsigned int*)(Mout + (size_t)n * HIDC + coff) =
            pack2(accx * inv, accy * inv);
    }
}

// ---------------------------------------------------------------------------
// Mean aggregation + BN affine on the MEAN (affine commutes; deg==0 -> 0).
// stats is NSLOT-slotted. Separate kernel so the plain pass stays lean.
// ---------------------------------------------------------------------------
__global__ __launch_bounds__(256) void agg_bn_kernel(
    const ushort_t* __restrict__ F, const int* __restrict__ row_ptr,
    const int* __restrict__ col, ushort_t* __restrict__ Mout,
    const float* __restrict__ preStats, const float* __restrict__ preG,
    const float* __restrict__ preBe)
{
    const int lane = threadIdx.x & 63;
    const int wave = blockIdx.x * 4 + (threadIdx.x >> 6);
    const int nwaves = gridDim.x * 4;
    const int coff = lane * 2;

    float s0 = 0.0f, s1 = 0.0f, q0 = 0.0f, q1 = 0.0f;
    #pragma unroll
    for (int s8 = 0; s8 < NSLOT; s8++) {
        s0 += preStats[s8 * 256 + coff];
        s1 += preStats[s8 * 256 + coff + 1];
        q0 += preStats[s8 * 256 + 128 + coff];
        q1 += preStats[s8 * 256 + 128 + coff + 1];
    }
    const float invM = 1.0f / (float)NN;
    const float m0 = s0 * invM;
    const float m1 = s1 * invM;
    float v0_ = q0 * invM - m0 * m0;
    float v1_ = q1 * invM - m1 * m1;
    if (v0_ < 0.0f) v0_ = 0.0f;
    if (v1_ < 0.0f) v1_ = 0.0f;
    const float sc0 = preG[coff] / sqrtf(v0_ + EPSC);
    const float sc1 = preG[coff + 1] / sqrtf(v1_ + EPSC);
    const float sh0 = preBe[coff] - m0 * sc0;
    const float sh1 = preBe[coff + 1] - m1 * sc1;

    for (int n = wave; n < NN; n += nwaves) {
        const int b = __builtin_amdgcn_readfirstlane(row_ptr[n]);
        const int e = __builtin_amdgcn_readfirstlane(row_ptr[n + 1]);
        const int deg = e - b;
        float accx = 0.0f, accy = 0.0f;
        int j = b;
        for (; j + 8 <= e; j += 8) {
            const int s0_ = col[j + 0];
            const int s1_ = col[j + 1];
            const int s2_ = col[j + 2];
            const int s3_ = col[j + 3];
            const int s4_ = col[j + 4];
            const int s5_ = col[j + 5];
            const int s6_ = col[j + 6];
            const int s7_ = col[j + 7];
            const unsigned int v0 = *(const unsigned int*)(F + (size_t)s0_ * HIDC + coff);
            const unsigned int v1 = *(const unsigned int*)(F + (size_t)s1_ * HIDC + coff);
            const unsigned int v2 = *(const unsigned int*)(F + (size_t)s2_ * HIDC + coff);
            const unsigned int v3 = *(const unsigned int*)(F + (size_t)s3_ * HIDC + coff);
            const unsigned int v4 = *(const unsigned int*)(F + (size_t)s4_ * HIDC + coff);
            const unsigned int v5 = *(const unsigned int*)(F + (size_t)s5_ * HIDC + coff);
            const unsigned int v6 = *(const unsigned int*)(F + (size_t)s6_ * HIDC + coff);
            const unsigned int v7 = *(const unsigned int*)(F + (size_t)s7_ * HIDC + coff);
            accx += bf2f(v0 & 0xffffu) + bf2f(v1 & 0xffffu) + bf2f(v2 & 0xffffu)
                  + bf2f(v3 & 0xffffu) + bf2f(v4 & 0xffffu) + bf2f(v5 & 0xffffu)
                  + bf2f(v6 & 0xffffu) + bf2f(v7 & 0xffffu);
            accy += bf2f(v0 >> 16) + bf2f(v1 >> 16) + bf2f(v2 >> 16)
                  + bf2f(v3 >> 16) + bf2f(v4 >> 16) + bf2f(v5 >> 16)
                  + bf2f(v6 >> 16) + bf2f(v7 >> 16);
        }
        for (; j < e; j++) {
            const unsigned int v = *(const unsigned int*)(F + (size_t)col[j] * HIDC + coff);
            accx += bf2f(v & 0xffffu);
            accy += bf2f(v >> 16);
        }
        float ox, oy;
        if (deg == 0) {
            ox = 0.0f; oy = 0.0f;
        } else {
            const float inv = 1.0f / (float)deg;
            ox = accx * inv * sc0 + sh0;
            oy = accy * inv * sc1 + sh1;
        }
        *(unsigned int*)(Mout + (size_t)n * HIDC + coff) = pack2(ox, oy);
    }
}

// ---------------------------------------------------------------------------
extern "C" void kernel_launch(void* const* d_in, const int* in_sizes, int n_in,
                              void* d_out, int out_size, void* d_ws, size_t ws_size,
                              hipStream_t stream)
{
    const float* x     = (const float*)d_in[0];
    const int*   ei    = (const int*)  d_in[1];
    const float* W_in  = (const float*)d_in[2];
    const float* b_in  = (const float*)d_in[3];
    const float* g1    = (const float*)d_in[4];
    const float* be1   = (const float*)d_in[5];
    const float* W_hid = (const float*)d_in[6];
    const float* b_hid = (const float*)d_in[7];
    const float* g2    = (const float*)d_in[8];
    const float* be2   = (const float*)d_in[9];
    const float* Wl1   = (const float*)d_in[10];
    const float* bl1   = (const float*)d_in[11];
    const float* Wr1   = (const float*)d_in[12];
    const float* g3    = (const float*)d_in[13];
    const float* be3   = (const float*)d_in[14];
    const float* Wl2   = (const float*)d_in[15];
    const float* bl2   = (const float*)d_in[16];
    const float* Wr2   = (const float*)d_in[17];
    const float* g4    = (const float*)d_in[18];
    const float* be4   = (const float*)d_in[19];

    const int* srcArr = ei;        // edge_index[0]
    const int* dstArr = ei + EE;   // edge_index[1]

    char* ws = (char*)d_ws;
    float*    bufA      = (float*)ws;    ws += (size_t)NN * HIDC * sizeof(float);
    float*    bufB      = (float*)ws;    ws += (size_t)NN * HIDC * sizeof(float);
    ushort_t* featB16   = (ushort_t*)ws; ws += (size_t)NN * HIDC * sizeof(ushort_t);
    ushort_t* o3B16     = (ushort_t*)ws; ws += (size_t)NN * HIDC * sizeof(ushort_t);
    ushort_t* aggB16    = (ushort_t*)ws; ws += (size_t)NN * HIDC * sizeof(ushort_t);
    float*    stats     = (float*)ws;    ws += 4 * STATS_STRIDE * sizeof(float);
    int*      hist2D    = (int*)ws;      ws += (size_t)NB * GA * sizeof(int);
    int*      rowTot    = (int*)ws;      ws += (NB + 4) * sizeof(int);
    int*      bucketBase= (int*)ws;      ws += (NB + 4) * sizeof(int);
    int*      rowp      = (int*)ws;      ws += (size_t)(NN + 4) * sizeof(int);
    int*      colIdx    = (int*)ws;      ws += (size_t)EE * sizeof(int);
    unsigned int* ebuf  = (unsigned int*)ws; ws += (size_t)EE * sizeof(unsigned int);
    ushort_t* Wt_in     = (ushort_t*)ws; ws += 128 * 256 * sizeof(ushort_t);
    ushort_t* Wt_hid    = (ushort_t*)ws; ws += 128 * 128 * sizeof(ushort_t);
    ushort_t* Wtl1      = (ushort_t*)ws; ws += 128 * 128 * sizeof(ushort_t);
    ushort_t* Wtr1      = (ushort_t*)ws; ws += 128 * 128 * sizeof(ushort_t);
    ushort_t* Wtl2      = (ushort_t*)ws; ws += 128 * 128 * sizeof(ushort_t);
    ushort_t* Wtr2      = (ushort_t*)ws; ws += 128 * 128 * sizeof(ushort_t);

    float* out0 = (float*)d_out;             // feat  [NN*HID] fp32
    float* out1 = out0 + (size_t)NN * HIDC;  // out   [NN*HID] fp32

    // zero: stats only (counting sort is store-based, nothing else needs init)
    hipMemsetAsync(stats, 0, 4 * STATS_STRIDE * sizeof(float), stream);

    // weight transpose + bf16 convert (one launch, 448 blocks)
    tcvt_all_kernel<<<448, 256, 0, stream>>>(W_in, W_hid, Wl1, Wr1, Wl2, Wr2,
                                             Wt_in, Wt_hid, Wtl1, Wtr1, Wtl2, Wtr2);

    // CSR build — atomic-free counting sort (packed edges, int col)
    bucket_hist_kernel<<<GA, 256, 0, stream>>>(dstArr, hist2D);
    bucket_scan_kernel<<<NB, 256, 0, stream>>>(hist2D, rowTot);
    bucket_base_kernel<<<1, 256, 0, stream>>>(rowTot, bucketBase, rowp);
    bucket_scatter_kernel<<<GA, 256, 0, stream>>>(srcArr, dstArr, hist2D,
                                                  bucketBase, ebuf);
    fine_sort_kernel<<<NB, 256, 0, stream>>>(ebuf, bucketBase, rowp, colIdx);

    const int gemmGrid = (NN + 63) / 64;   // 782 blocks x 512 threads

    // stage 1: input linear (x fp32, K=256) -> bufA fp32 + stats0
    mfma_gemm_kernel<<<gemmGrid, 512, 0, stream>>>(
        x, Wt_in, IN_DIMC, 0, nullptr, nullptr, 0,
        b_in, bufA, nullptr, NN, -1, 0, nullptr, nullptr, nullptr,
        stats + 0 * STATS_STRIDE);

    // stage 2: hidden linear, BN1+relu fused on A-load -> bufB fp32 + stats1
    mfma_gemm_kernel<<<gemmGrid, 512, 0, stream>>>(
        bufA, Wt_hid, HIDC, 0, nullptr, nullptr, 0,
        b_hid, bufB, nullptr, NN, 0, 1, stats + 0 * STATS_STRIDE, g1, be1,
        stats + 1 * STATS_STRIDE);

    // BN2+relu -> out0 (fp32) + featB16 (bf16)
    bn_apply_kernel<<<1024, 256, 0, stream>>>(bufB, out0, featB16,
                                              stats + 1 * STATS_STRIDE, g2, be2, 1, NN);

    // stage 3: SAGE1 -> o3B16 RAW bf16 (BN3 deferred: affine commutes w/ mean)
    agg_kernel<<<4096, 256, 0, stream>>>(featB16, rowp, colIdx, aggB16);
    mfma_gemm_kernel<<<gemmGrid, 512, 0, stream>>>(
        aggB16, Wtl1, HIDC, 1, featB16, Wtr1, HIDC,
        bl1, nullptr, o3B16, NN, -1, 0, nullptr, nullptr, nullptr,
        stats + 2 * STATS_STRIDE);

    // stage 4: SAGE2 — agg applies BN3 to the mean; GEMM applies BN3 on A2
    agg_bn_kernel<<<4096, 256, 0, stream>>>(o3B16, rowp, colIdx, aggB16,
                                            stats + 2 * STATS_STRIDE, g3, be3);
    mfma_gemm_kernel<<<gemmGrid, 512, 0, stream>>>(
        aggB16, Wtl2, HIDC, 1, o3B16, Wtr2, HIDC,
        bl2, bufB, nullptr, NN, 1, 0, stats + 2 * STATS_STRIDE, g3, be3,
        stats + 3 * STATS_STRIDE);

    // BN4 -> out1 (fp32)
    bn_apply_kernel<<<1024, 256, 0, stream>>>(bufB, out1, nullptr,
                                              stats + 3 * STATS_STRIDE, g4, be4, 0, NN);
}

// Round 10
// 441.285 us; speedup vs baseline: 1.1046x; 1.1046x over previous
//
#include <hip/hip_runtime.h>
#include <stdint.h>

#define NN 50000
#define EE 1600000
#define IN_DIMC 256
#define HIDC 128
#define EPSC 1e-5f

// counting-sort geometry
#define NB 196        // coarse buckets: dst>>8, 256 nodes/bucket (196*256 >= 50000)
#define GA 512        // phase-A blocks
#define CHUNK 3125    // EE / GA exactly
#define STILE_SHIFT 13   // src tile = src>>13 -> 7 tiles over 50000 nodes
#define NKEY 2048        // fine keys: (dst&255)<<3 | srctile

#define NSLOT 8          // stats atomic slots (contention /8)
#define STATS_STRIDE (NSLOT * 256)   // floats per stage

typedef unsigned short ushort_t;
typedef __attribute__((ext_vector_type(8))) short short8;
typedef __attribute__((ext_vector_type(4))) float floatx4;

static __device__ inline ushort_t f2bf(float f) {
    unsigned int u = __float_as_uint(f);
    u = u + 0x7fffu + ((u >> 16) & 1u);   // RNE
    return (ushort_t)(u >> 16);
}
static __device__ inline unsigned int pack2(float a, float b) {
    return (unsigned int)f2bf(a) | ((unsigned int)f2bf(b) << 16);
}
static __device__ inline float bf2f(unsigned int bits16) {
    return __uint_as_float(bits16 << 16);
}

// ---------------------------------------------------------------------------
// All six weight transposes + bf16 convert in ONE launch.
// ---------------------------------------------------------------------------
__global__ __launch_bounds__(256) void tcvt_all_kernel(
    const float* __restrict__ W_in, const float* __restrict__ W_hid,
    const float* __restrict__ Wl1, const float* __restrict__ Wr1,
    const float* __restrict__ Wl2, const float* __restrict__ Wr2,
    ushort_t* __restrict__ Wt_in, ushort_t* __restrict__ Wt_hid,
    ushort_t* __restrict__ Wtl1, ushort_t* __restrict__ Wtr1,
    ushort_t* __restrict__ Wtl2, ushort_t* __restrict__ Wtr2)
{
    const int idx = blockIdx.x * 256 + threadIdx.x;
    if (idx < 32768) {
        const int n = idx >> 8;           // /256
        const int k = idx & 255;
        Wt_in[idx] = f2bf(W_in[(size_t)k * 128 + n]);
    } else if (idx < 32768 + 5 * 16384) {
        const int r = idx - 32768;
        const int seg = r / 16384;
        const int j = r - seg * 16384;
        const int n = j >> 7;
        const int k = j & 127;
        const float* W; ushort_t* Wt;
        switch (seg) {
            case 0: W = W_hid; Wt = Wt_hid; break;
            case 1: W = Wl1;  Wt = Wtl1;  break;
            case 2: W = Wr1;  Wt = Wtr1;  break;
            case 3: W = Wl2;  Wt = Wtl2;  break;
            default: W = Wr2; Wt = Wtr2;  break;
        }
        Wt[j] = f2bf(W[(size_t)k * 128 + n]);
    }
}

// ---------------------------------------------------------------------------
// MFMA GEMM v5.4: v5.1 body + __launch_bounds__(512,6).
// 6 waves/EU -> VGPR budget 512/6 = 85, above the ~70 natural need (no
// spill; rd9's (512,8)=64-budget spilled: WRITE_SIZE 26->124MB, dur 80us),
// while allowing 3 blocks/CU (24 waves, LDS 3x40KB=120<=160KB).
// 512-thread blocks (8 waves), 64 rows/block, wave-tile 16 rows x 64 cols.
// B panel (128xK-chunk) staged once into LDS shared by 8 waves.
// A fragments per lane: row = lane&15, k = ks*32 + (lane>>4)*8 (verified).
// affineSeg: -1 none, 0/1 = apply BN affine (+optional relu) on that A's load.
// preStats/outStats are NSLOT-slotted (slot = blockIdx & 7).
// ---------------------------------------------------------------------------
__global__ __launch_bounds__(512, 6) void mfma_gemm_kernel(
    const void* __restrict__ A1, const ushort_t* __restrict__ Wt1, int K1, int a1type,
    const void* __restrict__ A2, const ushort_t* __restrict__ Wt2, int K2,
    const float* __restrict__ bias, float* __restrict__ Cf, ushort_t* __restrict__ Cb,
    int M, int affineSeg, int affineRelu,
    const float* __restrict__ preStats, const float* __restrict__ preG,
    const float* __restrict__ preBe, float* __restrict__ outStats)
{
    __shared__ ushort_t Bs[128 * 136];                 // 34816 B
    __shared__ __align__(16) float aArr[128], bArr[128];
    __shared__ float red_s[4][128], red_q[4][128];

    const int t    = threadIdx.x;          // 0..511
    const int lane = t & 63;
    const int wave = t >> 6;               // 0..7
    const int mt   = wave >> 1;            // 0..3 row sub-tile
    const int nh   = wave & 1;             // col half
    const int quad = lane >> 4;
    const int l15  = lane & 15;
    const int row0 = blockIdx.x * 64;
    const int rowW = row0 + mt * 16;       // wave's 16 rows
    const int ksq  = quad * 8;

    if (affineSeg >= 0 && t < 128) {
        float sS = 0.0f, sQ = 0.0f;
        #pragma unroll
        for (int s8 = 0; s8 < NSLOT; s8++) {
            sS += preStats[s8 * 256 + t];
            sQ += preStats[s8 * 256 + 128 + t];
        }
        const float invM = 1.0f / (float)M;
        const float mean = sS * invM;
        float var = sQ * invM - mean * mean;
        if (var < 0.0f) var = 0.0f;
        const float s = preG[t] / sqrtf(var + EPSC);
        aArr[t] = s;
        bArr[t] = preBe[t] - mean * s;
    }
    // aArr/bArr consumed only after the first staging __syncthreads()

    floatx4 acc[4];
    #pragma unroll
    for (int j = 0; j < 4; j++)
        acc[j] = (floatx4){0.0f, 0.0f, 0.0f, 0.0f};

    int gr = rowW + l15;
    if (gr > M - 1) gr = M - 1;

    bool firstChunk = true;

    for (int s = 0; s < 2; s++) {
        const void*     A     = s ? A2  : A1;
        const ushort_t* Wt    = s ? Wt2 : Wt1;
        const int       K     = s ? K2  : K1;
        const int       atype = s ? 1   : a1type;
        const int       doAf  = (affineSeg == s);
        if (A == nullptr) continue;

        for (int kc = 0; kc < K; kc += 128) {
            if (!firstChunk) __syncthreads();   // protect Bs until prior compute done
            firstChunk = false;

            // ---- stage B panel: 128 rows x 128 K bf16 (32 KB), 4 uint4/thread ----
            #pragma unroll
            for (int p = 0; p < 4; p++) {
                const int idx = p * 512 + t;    // 0..2047
                const int n   = idx >> 4;
                const int c0  = (idx & 15) * 8;
                *(uint4*)(Bs + n * 136 + c0) =
                    *(const uint4*)(Wt + (size_t)n * K + kc + c0);
            }
            __syncthreads();

            // ---- A fragments: 4 k-steps, per-lane, direct global->VGPR ----
            short8 afrag[4];
            if (atype == 1) {
                const ushort_t* Ab = (const ushort_t*)A;
                const size_t base = (size_t)gr * K + kc + ksq;
                #pragma unroll
                for (int ks = 0; ks < 4; ks++)
                    afrag[ks] = *(const short8*)(Ab + base + ks * 32);
                if (doAf) {
                    #pragma unroll
                    for (int ks = 0; ks < 4; ks++) {
                        const int k0 = ks * 32 + ksq;   // K==128 when affine
                        uint4 u = __builtin_bit_cast(uint4, afrag[ks]);
                        uint4 w;
                        unsigned int* up = (unsigned int*)&u;
                        unsigned int* wp = (unsigned int*)&w;
                        #pragma unroll
                        for (int h = 0; h < 4; h++) {
                            float lo = aArr[k0 + h * 2]     * bf2f(up[h] & 0xffffu) + bArr[k0 + h * 2];
                            float hi = aArr[k0 + h * 2 + 1] * bf2f(up[h] >> 16)     + bArr[k0 + h * 2 + 1];
                            if (affineRelu) { lo = fmaxf(lo, 0.0f); hi = fmaxf(hi, 0.0f); }
                            wp[h] = pack2(lo, hi);
                        }
                        afrag[ks] = __builtin_bit_cast(short8, w);
                    }
                }
            } else {
                const float* Af = (const float*)A;
                const size_t base = (size_t)gr * K + kc + ksq;
                #pragma unroll
                for (int ks = 0; ks < 4; ks++) {
                    float4 v0 = *(const float4*)(Af + base + ks * 32);
                    float4 v1 = *(const float4*)(Af + base + ks * 32 + 4);
                    if (doAf) {
                        const int k0 = ks * 32 + ksq;
                        const float4 sa0 = *(const float4*)(aArr + k0);
                        const float4 sb0 = *(const float4*)(bArr + k0);
                        const float4 sa1 = *(const float4*)(aArr + k0 + 4);
                        const float4 sb1 = *(const float4*)(bArr + k0 + 4);
                        v0.x = sa0.x * v0.x + sb0.x;
                        v0.y = sa0.y * v0.y + sb0.y;
                        v0.z = sa0.z * v0.z + sb0.z;
                        v0.w = sa0.w * v0.w + sb0.w;
                        v1.x = sa1.x * v1.x + sb1.x;
                        v1.y = sa1.y * v1.y + sb1.y;
                        v1.z = sa1.z * v1.z + sb1.z;
                        v1.w = sa1.w * v1.w + sb1.w;
                        if (affineRelu) {
                            v0.x = fmaxf(v0.x, 0.0f); v0.y = fmaxf(v0.y, 0.0f);
                            v0.z = fmaxf(v0.z, 0.0f); v0.w = fmaxf(v0.w, 0.0f);
                            v1.x = fmaxf(v1.x, 0.0f); v1.y = fmaxf(v1.y, 0.0f);
                            v1.z = fmaxf(v1.z, 0.0f); v1.w = fmaxf(v1.w, 0.0f);
                        }
                    }
                    uint4 w;
                    w.x = pack2(v0.x, v0.y);
                    w.y = pack2(v0.z, v0.w);
                    w.z = pack2(v1.x, v1.y);
                    w.w = pack2(v1.z, v1.w);
                    afrag[ks] = __builtin_bit_cast(short8, w);
                }
            }

            // ---- compute: wave's 64 cols (nh half), ks outer ----
            #pragma unroll
            for (int ks = 0; ks < 4; ks++) {
                const int ko = ks * 32 + ksq;
                short8 b[4];
                #pragma unroll
                for (int j = 0; j < 4; j++)
                    b[j] = *(const short8*)(Bs + (nh * 64 + j * 16 + l15) * 136 + ko);
                #pragma unroll
                for (int j = 0; j < 4; j++)
                    acc[j] = __builtin_amdgcn_mfma_f32_16x16x32_bf16(
                        afrag[ks], b[j], acc[j], 0, 0, 0);
            }
        }
    }

    // ---- epilogue: bias, C store (fp32 and/or bf16), per-column stats ----
    float s_[4], q_[4];
    #pragma unroll
    for (int j = 0; j < 4; j++) { s_[j] = 0.0f; q_[j] = 0.0f; }

    #pragma unroll
    for (int j = 0; j < 4; j++) {
        const int col = nh * 64 + j * 16 + l15;
        const float bv = bias[col];
        const int rbase = rowW + quad * 4;
        #pragma unroll
        for (int reg = 0; reg < 4; reg++) {
            const float val = acc[j][reg] + bv;
            const int r_ = rbase + reg;
            if (r_ < M) {
                if (Cf) Cf[(size_t)r_ * HIDC + col] = val;
                if (Cb) Cb[(size_t)r_ * HIDC + col] = f2bf(val);
                s_[j] += val;
                q_[j] += val * val;
            }
        }
    }
    #pragma unroll
    for (int j = 0; j < 4; j++) {
        s_[j] += __shfl_xor(s_[j], 16, 64);
        s_[j] += __shfl_xor(s_[j], 32, 64);
        q_[j] += __shfl_xor(q_[j], 16, 64);
        q_[j] += __shfl_xor(q_[j], 32, 64);
    }
    if (quad == 0) {
        #pragma unroll
        for (int j = 0; j < 4; j++) {
            red_s[mt][nh * 64 + j * 16 + l15] = s_[j];
            red_q[mt][nh * 64 + j * 16 + l15] = q_[j];
        }
    }
    __syncthreads();
    if (t < 128) {
        const float S = red_s[0][t] + red_s[1][t] + red_s[2][t] + red_s[3][t];
        const float Q = red_q[0][t] + red_q[1][t] + red_q[2][t] + red_q[3][t];
        float* slot = outStats + (blockIdx.x & (NSLOT - 1)) * 256;
        atomicAdd(&slot[t], S);
        atomicAdd(&slot[128 + t], Q);
    }
}

// ---------------------------------------------------------------------------
// BN apply: dst fp32 (optional) and/or dst bf16 (optional), + optional relu.
// stats is NSLOT-slotted.
// ---------------------------------------------------------------------------
__global__ __launch_bounds__(256) void bn_apply_kernel(
    const float* __restrict__ src, float* __restrict__ dstF,
    ushort_t* __restrict__ dstB, const float* __restrict__ stats,
    const float* __restrict__ gamma, const float* __restrict__ beta,
    int relu, int M)
{
    __shared__ float sc[128], sh[128];
    const int t = threadIdx.x;
    if (t < 128) {
        float sS = 0.0f, sQ = 0.0f;
        #pragma unroll
        for (int s8 = 0; s8 < NSLOT; s8++) {
            sS += stats[s8 * 256 + t];
            sQ += stats[s8 * 256 + 128 + t];
        }
        const float invM = 1.0f / (float)M;
        const float mean = sS * invM;
        float var = sQ * invM - mean * mean;
        if (var < 0.0f) var = 0.0f;
        const float s = gamma[t] / sqrtf(var + EPSC);
        sc[t] = s;
        sh[t] = beta[t] - mean * s;
    }
    __syncthreads();

    const int total4 = M * HIDC / 4;
    for (int i = blockIdx.x * 256 + t; i < total4; i += gridDim.x * 256) {
        float4 v = ((const float4*)src)[i];
        const int c = (i * 4) & 127;
        v.x = v.x * sc[c]     + sh[c];
        v.y = v.y * sc[c + 1] + sh[c + 1];
        v.z = v.z * sc[c + 2] + sh[c + 2];
        v.w = v.w * sc[c + 3] + sh[c + 3];
        if (relu) {
            v.x = fmaxf(v.x, 0.0f); v.y = fmaxf(v.y, 0.0f);
            v.z = fmaxf(v.z, 0.0f); v.w = fmaxf(v.w, 0.0f);
        }
        if (dstF) ((float4*)dstF)[i] = v;
        if (dstB) {
            uint2 w;
            w.x = pack2(v.x, v.y);
            w.y = pack2(v.z, v.w);
            *(uint2*)(dstB + (size_t)i * 4) = w;
        }
    }
}

// ---------------------------------------------------------------------------
// CSR build — atomic-free two-level counting sort. Edges packed 32-bit
// (src<<16 | dst). Fine phase orders by (dst&255, srctile). col is INT.
// ---------------------------------------------------------------------------
__global__ __launch_bounds__(256) void bucket_hist_kernel(
    const int* __restrict__ dstArr, int* __restrict__ hist2D)
{
    __shared__ int hist[NB];
    const int t = threadIdx.x;
    for (int i = t; i < NB; i += 256) hist[i] = 0;
    __syncthreads();
    const int e0 = blockIdx.x * CHUNK;
    const int e1 = e0 + CHUNK;   // EE = GA*CHUNK exactly
    for (int e = e0 + t; e < e1; e += 256)
        atomicAdd(&hist[dstArr[e] >> 8], 1);
    __syncthreads();
    for (int i = t; i < NB; i += 256)
        hist2D[(size_t)i * GA + blockIdx.x] = hist[i];
}

// per-bucket exclusive scan over the GA=512 phase-A block counts.
__global__ __launch_bounds__(256) void bucket_scan_kernel(
    int* __restrict__ hist2D, int* __restrict__ rowTot)
{
    __shared__ int wtot[4];
    const int b = blockIdx.x;
    const int t = threadIdx.x;
    int* row = hist2D + (size_t)b * GA;
    const int v0 = row[2 * t];
    const int v1 = row[2 * t + 1];
    const int pair = v0 + v1;
    const int lane = t & 63, w = t >> 6;
    int x = pair;
    #pragma unroll
    for (int off = 1; off < 64; off <<= 1) {
        const int y = __shfl_up(x, off);
        if (lane >= off) x += y;
    }
    if (lane == 63) wtot[w] = x;
    __syncthreads();
    int woff = 0;
    #pragma unroll
    for (int j = 0; j < 4; j++) if (j < w) woff += wtot[j];
    const int excl = x + woff - pair;
    row[2 * t]     = excl;
    row[2 * t + 1] = excl + v0;
    if (t == 255) rowTot[b] = excl + pair;
}

// 1 block: exclusive scan of NB bucket totals -> bucketBase.
__global__ __launch_bounds__(256) void bucket_base_kernel(
    const int* __restrict__ rowTot, int* __restrict__ bucketBase,
    int* __restrict__ rowp)
{
    __shared__ int wtot[4];
    const int t = threadIdx.x;
    const int tot = (t < NB) ? rowTot[t] : 0;
    const int lane = t & 63, w = t >> 6;
    int x = tot;
    #pragma unroll
    for (int off = 1; off < 64; off <<= 1) {
        const int y = __shfl_up(x, off);
        if (lane >= off) x += y;
    }
    if (lane == 63) wtot[w] = x;
    __syncthreads();
    int woff = 0;
    #pragma unroll
    for (int j = 0; j < 4; j++) if (j < w) woff += wtot[j];
    const int excl = x + woff - tot;
    if (t < NB) bucketBase[t] = excl;
    if (t == 0) { bucketBase[NB] = EE; rowp[NN] = EE; }
}

__global__ __launch_bounds__(256) void bucket_scatter_kernel(
    const int* __restrict__ srcArr, const int* __restrict__ dstArr,
    const int* __restrict__ hist2D, const int* __restrict__ bucketBase,
    unsigned int* __restrict__ ebuf)
{
    __shared__ int cur[NB];
    const int t = threadIdx.x;
    for (int i = t; i < NB; i += 256)
        cur[i] = bucketBase[i] + hist2D[(size_t)i * GA + blockIdx.x];
    __syncthreads();
    const int e0 = blockIdx.x * CHUNK;
    const int e1 = e0 + CHUNK;
    for (int e = e0 + t; e < e1; e += 256) {
        const int d = dstArr[e];
        const int s = srcArr[e];
        const int p = atomicAdd(&cur[d >> 8], 1);
        ebuf[p] = ((unsigned int)s << 16) | (unsigned int)d;
    }
}

__global__ __launch_bounds__(256) void fine_sort_kernel(
    const unsigned int* __restrict__ ebuf, const int* __restrict__ bucketBase,
    int* __restrict__ rowp, int* __restrict__ col)
{
    __shared__ int cnt[NKEY];       // 8 KB: (dst&255)<<3 | srctile
    __shared__ int wtot[4];
    const int b = blockIdx.x;
    const int t = threadIdx.x;
    const int bb0 = bucketBase[b];
    const int bb1 = bucketBase[b + 1];
    #pragma unroll
    for (int i = 0; i < 8; i++) cnt[t * 8 + i] = 0;
    __syncthreads();
    for (int e = bb0 + t; e < bb1; e += 256) {
        const unsigned int sd = ebuf[e];
        const int key = (int)((sd & 255u) << 3) | (int)(sd >> (16 + STILE_SHIFT));
        atomicAdd(&cnt[key], 1);
    }
    __syncthreads();
    int loc[8];
    int tot = 0;
    #pragma unroll
    for (int i = 0; i < 8; i++) { loc[i] = tot; tot += cnt[t * 8 + i]; }
    const int lane = t & 63, w = t >> 6;
    int x = tot;
    #pragma unroll
    for (int off = 1; off < 64; off <<= 1) {
        const int y = __shfl_up(x, off);
        if (lane >= off) x += y;
    }
    if (lane == 63) wtot[w] = x;
    __syncthreads();
    int woff = 0;
    #pragma unroll
    for (int j = 0; j < 4; j++) if (j < w) woff += wtot[j];
    const int excl = x + woff - tot;
    const int node = b * 256 + t;
    if (node < NN) rowp[node] = bb0 + excl;
    __syncthreads();
    #pragma unroll
    for (int i = 0; i < 8; i++) cnt[t * 8 + i] = excl + loc[i];  // cursors
    __syncthreads();
    for (int e = bb0 + t; e < bb1; e += 256) {
        const unsigned int sd = ebuf[e];
        const int key = (int)((sd & 255u) << 3) | (int)(sd >> (16 + STILE_SHIFT));
        const int p = atomicAdd(&cnt[key], 1);
        col[bb0 + p] = (int)(sd >> 16);
    }
}

// ---------------------------------------------------------------------------
// Mean aggregation (plain): one wave per node, 2 cols/lane, grid-stride over
// 16384 waves — round-1's empirically-best shape, zero affine overhead.
// ---------------------------------------------------------------------------
__global__ __launch_bounds__(256) void agg_kernel(
    const ushort_t* __restrict__ F, const int* __restrict__ row_ptr,
    const int* __restrict__ col, ushort_t* __restrict__ Mout)
{
    const int lane = threadIdx.x & 63;
    const int wave = blockIdx.x * 4 + (threadIdx.x >> 6);
    const int nwaves = gridDim.x * 4;
    const int coff = lane * 2;

    for (int n = wave; n < NN; n += nwaves) {
        const int b = __builtin_amdgcn_readfirstlane(row_ptr[n]);
        const int e = __builtin_amdgcn_readfirstlane(row_ptr[n + 1]);
        const int deg = e - b;
        float accx = 0.0f, accy = 0.0f;
        int j = b;
        for (; j + 8 <= e; j += 8) {
            const int s0 = col[j + 0];
            const int s1 = col[j + 1];
            const int s2 = col[j + 2];
            const int s3 = col[j + 3];
            const int s4 = col[j + 4];
            const int s5 = col[j + 5];
            const int s6 = col[j + 6];
            const int s7 = col[j + 7];
            const unsigned int v0 = *(const unsigned int*)(F + (size_t)s0 * HIDC + coff);
            const unsigned int v1 = *(const unsigned int*)(F + (size_t)s1 * HIDC + coff);
            const unsigned int v2 = *(const unsigned int*)(F + (size_t)s2 * HIDC + coff);
            const unsigned int v3 = *(const unsigned int*)(F + (size_t)s3 * HIDC + coff);
            const unsigned int v4 = *(const unsigned int*)(F + (size_t)s4 * HIDC + coff);
            const unsigned int v5 = *(const unsigned int*)(F + (size_t)s5 * HIDC + coff);
            const unsigned int v6 = *(const unsigned int*)(F + (size_t)s6 * HIDC + coff);
            const unsigned int v7 = *(const unsigned int*)(F + (size_t)s7 * HIDC + coff);
            accx += bf2f(v0 & 0xffffu) + bf2f(v1 & 0xffffu) + bf2f(v2 & 0xffffu)
                  + bf2f(v3 & 0xffffu) + bf2f(v4 & 0xffffu) + bf2f(v5 & 0xffffu)
                  + bf2f(v6 & 0xffffu) + bf2f(v7 & 0xffffu);
            accy += bf2f(v0 >> 16) + bf2f(v1 >> 16) + bf2f(v2 >> 16)
                  + bf2f(v3 >> 16) + bf2f(v4 >> 16) + bf2f(v5 >> 16)
                  + bf2f(v6 >> 16) + bf2f(v7 >> 16);
        }
        for (; j < e; j++) {
            const unsigned int v = *(const unsigned int*)(F + (size_t)col[j] * HIDC + coff);
            accx += bf2f(v & 0xffffu);
            accy += bf2f(v >> 16);
        }
        const float inv = 1.0f / (float)(deg > 1 ? deg : 1);
        *(unsigned int*)(Mout + (size_t)n * HIDC + coff) =
            pack2(accx * inv, accy * inv);
    }
}

// ---------------------------------------------------------------------------
// Mean aggregation + BN affine on the MEAN (affine commutes; deg==0 -> 0).
// stats is NSLOT-slotted. Separate kernel so the plain pass stays lean.
// ---------------------------------------------------------------------------
__global__ __launch_bounds__(256) void agg_bn_kernel(
    const ushort_t* __restrict__ F, const int* __restrict__ row_ptr,
    const int* __restrict__ col, ushort_t* __restrict__ Mout,
    const float* __restrict__ preStats, const float* __restrict__ preG,
    const float* __restrict__ preBe)
{
    const int lane = threadIdx.x & 63;
    const int wave = blockIdx.x * 4 + (threadIdx.x >> 6);
    const int nwaves = gridDim.x * 4;
    const int coff = lane * 2;

    float s0 = 0.0f, s1 = 0.0f, q0 = 0.0f, q1 = 0.0f;
    #pragma unroll
    for (int s8 = 0; s8 < NSLOT; s8++) {
        s0 += preStats[s8 * 256 + coff];
        s1 += preStats[s8 * 256 + coff + 1];
        q0 += preStats[s8 * 256 + 128 + coff];
        q1 += preStats[s8 * 256 + 128 + coff + 1];
    }
    const float invM = 1.0f / (float)NN;
    const float m0 = s0 * invM;
    const float m1 = s1 * invM;
    float v0_ = q0 * invM - m0 * m0;
    float v1_ = q1 * invM - m1 * m1;
    if (v0_ < 0.0f) v0_ = 0.0f;
    if (v1_ < 0.0f) v1_ = 0.0f;
    const float sc0 = preG[coff] / sqrtf(v0_ + EPSC);
    const float sc1 = preG[coff + 1] / sqrtf(v1_ + EPSC);
    const float sh0 = preBe[coff] - m0 * sc0;
    const float sh1 = preBe[coff + 1] - m1 * sc1;

    for (int n = wave; n < NN; n += nwaves) {
        const int b = __builtin_amdgcn_readfirstlane(row_ptr[n]);
        const int e = __builtin_amdgcn_readfirstlane(row_ptr[n + 1]);
        const int deg = e - b;
        float accx = 0.0f, accy = 0.0f;
        int j = b;
        for (; j + 8 <= e; j += 8) {
            const int s0_ = col[j + 0];
            const int s1_ = col[j + 1];
            const int s2_ = col[j + 2];
            const int s3_ = col[j + 3];
            const int s4_ = col[j + 4];
            const int s5_ = col[j + 5];
            const int s6_ = col[j + 6];
            const int s7_ = col[j + 7];
            const unsigned int v0 = *(const unsigned int*)(F + (size_t)s0_ * HIDC + coff);
            const unsigned int v1 = *(const unsigned int*)(F + (size_t)s1_ * HIDC + coff);
            const unsigned int v2 = *(const unsigned int*)(F + (size_t)s2_ * HIDC + coff);
            const unsigned int v3 = *(const unsigned int*)(F + (size_t)s3_ * HIDC + coff);
            const unsigned int v4 = *(const unsigned int*)(F + (size_t)s4_ * HIDC + coff);
            const unsigned int v5 = *(const unsigned int*)(F + (size_t)s5_ * HIDC + coff);
            const unsigned int v6 = *(const unsigned int*)(F + (size_t)s6_ * HIDC + coff);
            const unsigned int v7 = *(const unsigned int*)(F + (size_t)s7_ * HIDC + coff);
            accx += bf2f(v0 & 0xffffu) + bf2f(v1 & 0xffffu) + bf2f(v2 & 0xffffu)
                  + bf2f(v3 & 0xffffu) + bf2f(v4 & 0xffffu) + bf2f(v5 & 0xffffu)
                  + bf2f(v6 & 0xffffu) + bf2f(v7 & 0xffffu);
            accy += bf2f(v0 >> 16) + bf2f(v1 >> 16) + bf2f(v2 >> 16)
                  + bf2f(v3 >> 16) + bf2f(v4 >> 16) + bf2f(v5 >> 16)
                  + bf2f(v6 >> 16) + bf2f(v7 >> 16);
        }
        for (; j < e; j++) {
            const unsigned int v = *(const unsigned int*)(F + (size_t)col[j] * HIDC + coff);
            accx += bf2f(v & 0xffffu);
            accy += bf2f(v >> 16);
        }
        float ox, oy;
        if (deg == 0) {
            ox = 0.0f; oy = 0.0f;
        } else {
            const float inv = 1.0f / (float)deg;
            ox = accx * inv * sc0 + sh0;
            oy = accy * inv * sc1 + sh1;
        }
        *(unsigned int*)(Mout + (size_t)n * HIDC + coff) = pack2(ox, oy);
    }
}

// ---------------------------------------------------------------------------
extern "C" void kernel_launch(void* const* d_in, const int* in_sizes, int n_in,
                              void* d_out, int out_size, void* d_ws, size_t ws_size,
                              hipStream_t stream)
{
    const float* x     = (const float*)d_in[0];
    const int*   ei    = (const int*)  d_in[1];
    const float* W_in  = (const float*)d_in[2];
    const float* b_in  = (const float*)d_in[3];
    const float* g1    = (const float*)d_in[4];
    const float* be1   = (const float*)d_in[5];
    const float* W_hid = (const float*)d_in[6];
    const float* b_hid = (const float*)d_in[7];
    const float* g2    = (const float*)d_in[8];
    const float* be2   = (const float*)d_in[9];
    const float* Wl1   = (const float*)d_in[10];
    const float* bl1   = (const float*)d_in[11];
    const float* Wr1   = (const float*)d_in[12];
    const float* g3    = (const float*)d_in[13];
    const float* be3   = (const float*)d_in[14];
    const float* Wl2   = (const float*)d_in[15];
    const float* bl2   = (const float*)d_in[16];
    const float* Wr2   = (const float*)d_in[17];
    const float* g4    = (const float*)d_in[18];
    const float* be4   = (const float*)d_in[19];

    const int* srcArr = ei;        // edge_index[0]
    const int* dstArr = ei + EE;   // edge_index[1]

    char* ws = (char*)d_ws;
    float*    bufA      = (float*)ws;    ws += (size_t)NN * HIDC * sizeof(float);
    float*    bufB      = (float*)ws;    ws += (size_t)NN * HIDC * sizeof(float);
    ushort_t* featB16   = (ushort_t*)ws; ws += (size_t)NN * HIDC * sizeof(ushort_t);
    ushort_t* o3B16     = (ushort_t*)ws; ws += (size_t)NN * HIDC * sizeof(ushort_t);
    ushort_t* aggB16    = (ushort_t*)ws; ws += (size_t)NN * HIDC * sizeof(ushort_t);
    float*    stats     = (float*)ws;    ws += 4 * STATS_STRIDE * sizeof(float);
    int*      hist2D    = (int*)ws;      ws += (size_t)NB * GA * sizeof(int);
    int*      rowTot    = (int*)ws;      ws += (NB + 4) * sizeof(int);
    int*      bucketBase= (int*)ws;      ws += (NB + 4) * sizeof(int);
    int*      rowp      = (int*)ws;      ws += (size_t)(NN + 4) * sizeof(int);
    int*      colIdx    = (int*)ws;      ws += (size_t)EE * sizeof(int);
    unsigned int* ebuf  = (unsigned int*)ws; ws += (size_t)EE * sizeof(unsigned int);
    ushort_t* Wt_in     = (ushort_t*)ws; ws += 128 * 256 * sizeof(ushort_t);
    ushort_t* Wt_hid    = (ushort_t*)ws; ws += 128 * 128 * sizeof(ushort_t);
    ushort_t* Wtl1      = (ushort_t*)ws; ws += 128 * 128 * sizeof(ushort_t);
    ushort_t* Wtr1      = (ushort_t*)ws; ws += 128 * 128 * sizeof(ushort_t);
    ushort_t* Wtl2      = (ushort_t*)ws; ws += 128 * 128 * sizeof(ushort_t);
    ushort_t* Wtr2      = (ushort_t*)ws; ws += 128 * 128 * sizeof(ushort_t);

    float* out0 = (float*)d_out;             // feat  [NN*HID] fp32
    float* out1 = out0 + (size_t)NN * HIDC;  // out   [NN*HID] fp32

    // zero: stats only (counting sort is store-based, nothing else needs init)
    hipMemsetAsync(stats, 0, 4 * STATS_STRIDE * sizeof(float), stream);

    // weight transpose + bf16 convert (one launch, 448 blocks)
    tcvt_all_kernel<<<448, 256, 0, stream>>>(W_in, W_hid, Wl1, Wr1, Wl2, Wr2,
                                             Wt_in, Wt_hid, Wtl1, Wtr1, Wtl2, Wtr2);

    // CSR build — atomic-free counting sort (packed edges, int col)
    bucket_hist_kernel<<<GA, 256, 0, stream>>>(dstArr, hist2D);
    bucket_scan_kernel<<<NB, 256, 0, stream>>>(hist2D, rowTot);
    bucket_base_kernel<<<1, 256, 0, stream>>>(rowTot, bucketBase, rowp);
    bucket_scatter_kernel<<<GA, 256, 0, stream>>>(srcArr, dstArr, hist2D,
                                                  bucketBase, ebuf);
    fine_sort_kernel<<<NB, 256, 0, stream>>>(ebuf, bucketBase, rowp, colIdx);

    const int gemmGrid = (NN + 63) / 64;   // 782 blocks x 512 threads

    // stage 1: input linear (x fp32, K=256) -> bufA fp32 + stats0
    mfma_gemm_kernel<<<gemmGrid, 512, 0, stream>>>(
        x, Wt_in, IN_DIMC, 0, nullptr, nullptr, 0,
        b_in, bufA, nullptr, NN, -1, 0, nullptr, nullptr, nullptr,
        stats + 0 * STATS_STRIDE);

    // stage 2: hidden linear, BN1+relu fused on A-load -> bufB fp32 + stats1
    mfma_gemm_kernel<<<gemmGrid, 512, 0, stream>>>(
        bufA, Wt_hid, HIDC, 0, nullptr, nullptr, 0,
        b_hid, bufB, nullptr, NN, 0, 1, stats + 0 * STATS_STRIDE, g1, be1,
        stats + 1 * STATS_STRIDE);

    // BN2+relu -> out0 (fp32) + featB16 (bf16)
    bn_apply_kernel<<<1024, 256, 0, stream>>>(bufB, out0, featB16,
                                              stats + 1 * STATS_STRIDE, g2, be2, 1, NN);

    // stage 3: SAGE1 -> o3B16 RAW bf16 (BN3 deferred: affine commutes w/ mean)
    agg_kernel<<<4096, 256, 0, stream>>>(featB16, rowp, colIdx, aggB16);
    mfma_gemm_kernel<<<gemmGrid, 512, 0, stream>>>(
        aggB16, Wtl1, HIDC, 1, featB16, Wtr1, HIDC,
        bl1, nullptr, o3B16, NN, -1, 0, nullptr, nullptr, nullptr,
        stats + 2 * STATS_STRIDE);

    // stage 4: SAGE2 — agg applies BN3 to the mean; GEMM applies BN3 on A2
    agg_bn_kernel<<<4096, 256, 0, stream>>>(o3B16, rowp, colIdx, aggB16,
                                            stats + 2 * STATS_STRIDE, g3, be3);
    mfma_gemm_kernel<<<gemmGrid, 512, 0, stream>>>(
        aggB16, Wtl2, HIDC, 1, o3B16, Wtr2, HIDC,
        bl2, bufB, nullptr, NN, 1, 0, stats + 2 * STATS_STRIDE, g3, be3,
        stats + 3 * STATS_STRIDE);

    // BN4 -> out1 (fp32)
    bn_apply_kernel<<<1024, 256, 0, stream>>>(bufB, out1, nullptr,
                                              stats + 3 * STATS_STRIDE, g4, be4, 0, NN);
}

// Round 11
// 387.305 us; speedup vs baseline: 1.2585x; 1.1394x over previous
//
#include <hip/hip_runtime.h>
#include <stdint.h>

#define NN 50000
#define EE 1600000
#define IN_DIMC 256
#define HIDC 128
#define EPSC 1e-5f

// counting-sort geometry
#define NB 196        // coarse buckets: dst>>8, 256 nodes/bucket (196*256 >= 50000)
#define GA 512        // phase-A blocks
#define CHUNK 3125    // EE / GA exactly
#define STILE_SHIFT 13   // src tile = src>>13 -> 7 tiles over 50000 nodes
#define NKEY 2048        // fine keys: (dst&255)<<3 | srctile

#define NSLOT 8          // stats atomic slots (contention /8)
#define STATS_STRIDE (NSLOT * 256)   // floats per stage

typedef unsigned short ushort_t;
typedef __attribute__((ext_vector_type(8))) short short8;
typedef __attribute__((ext_vector_type(4))) float floatx4;

static __device__ inline ushort_t f2bf(float f) {
    unsigned int u = __float_as_uint(f);
    u = u + 0x7fffu + ((u >> 16) & 1u);   // RNE
    return (ushort_t)(u >> 16);
}
static __device__ inline unsigned int pack2(float a, float b) {
    return (unsigned int)f2bf(a) | ((unsigned int)f2bf(b) << 16);
}
static __device__ inline float bf2f(unsigned int bits16) {
    return __uint_as_float(bits16 << 16);
}

// ---------------------------------------------------------------------------
// All six weight transposes + bf16 convert in ONE launch.
// ---------------------------------------------------------------------------
__global__ __launch_bounds__(256) void tcvt_all_kernel(
    const float* __restrict__ W_in, const float* __restrict__ W_hid,
    const float* __restrict__ Wl1, const float* __restrict__ Wr1,
    const float* __restrict__ Wl2, const float* __restrict__ Wr2,
    ushort_t* __restrict__ Wt_in, ushort_t* __restrict__ Wt_hid,
    ushort_t* __restrict__ Wtl1, ushort_t* __restrict__ Wtr1,
    ushort_t* __restrict__ Wtl2, ushort_t* __restrict__ Wtr2)
{
    const int idx = blockIdx.x * 256 + threadIdx.x;
    if (idx < 32768) {
        const int n = idx >> 8;           // /256
        const int k = idx & 255;
        Wt_in[idx] = f2bf(W_in[(size_t)k * 128 + n]);
    } else if (idx < 32768 + 5 * 16384) {
        const int r = idx - 32768;
        const int seg = r / 16384;
        const int j = r - seg * 16384;
        const int n = j >> 7;
        const int k = j & 127;
        const float* W; ushort_t* Wt;
        switch (seg) {
            case 0: W = W_hid; Wt = Wt_hid; break;
            case 1: W = Wl1;  Wt = Wtl1;  break;
            case 2: W = Wr1;  Wt = Wtr1;  break;
            case 3: W = Wl2;  Wt = Wtl2;  break;
            default: W = Wr2; Wt = Wtr2;  break;
        }
        Wt[j] = f2bf(W[(size_t)k * 128 + n]);
    }
}

// ---------------------------------------------------------------------------
// MFMA GEMM v5.5 == round-7's best-measured config: v5.1 body, NO occupancy
// bound (plain __launch_bounds__(512)). Measured facts: (512,8) -> VGPR 32
// w/ spill (WRITE 26->124MB, 80us); (512,6) -> ~+10us/launch vs unbounded;
// unbounded (R7) was fastest. This GEMM is ILP-bound: the compiler's natural
// ~4 waves/EU VGPR budget keeps more loads in flight than extra waves do.
// 512-thread blocks (8 waves), 64 rows/block, wave-tile 16 rows x 64 cols.
// B panel (128xK-chunk) staged once into LDS shared by 8 waves.
// A fragments per lane: row = lane&15, k = ks*32 + (lane>>4)*8 (verified).
// affineSeg: -1 none, 0/1 = apply BN affine (+optional relu) on that A's load.
// preStats/outStats are NSLOT-slotted (slot = blockIdx & 7).
// ---------------------------------------------------------------------------
__global__ __launch_bounds__(512) void mfma_gemm_kernel(
    const void* __restrict__ A1, const ushort_t* __restrict__ Wt1, int K1, int a1type,
    const void* __restrict__ A2, const ushort_t* __restrict__ Wt2, int K2,
    const float* __restrict__ bias, float* __restrict__ Cf, ushort_t* __restrict__ Cb,
    int M, int affineSeg, int affineRelu,
    const float* __restrict__ preStats, const float* __restrict__ preG,
    const float* __restrict__ preBe, float* __restrict__ outStats)
{
    __shared__ ushort_t Bs[128 * 136];                 // 34816 B
    __shared__ __align__(16) float aArr[128], bArr[128];
    __shared__ float red_s[4][128], red_q[4][128];

    const int t    = threadIdx.x;          // 0..511
    const int lane = t & 63;
    const int wave = t >> 6;               // 0..7
    const int mt   = wave >> 1;            // 0..3 row sub-tile
    const int nh   = wave & 1;             // col half
    const int quad = lane >> 4;
    const int l15  = lane & 15;
    const int row0 = blockIdx.x * 64;
    const int rowW = row0 + mt * 16;       // wave's 16 rows
    const int ksq  = quad * 8;

    if (affineSeg >= 0 && t < 128) {
        float sS = 0.0f, sQ = 0.0f;
        #pragma unroll
        for (int s8 = 0; s8 < NSLOT; s8++) {
            sS += preStats[s8 * 256 + t];
            sQ += preStats[s8 * 256 + 128 + t];
        }
        const float invM = 1.0f / (float)M;
        const float mean = sS * invM;
        float var = sQ * invM - mean * mean;
        if (var < 0.0f) var = 0.0f;
        const float s = preG[t] / sqrtf(var + EPSC);
        aArr[t] = s;
        bArr[t] = preBe[t] - mean * s;
    }
    // aArr/bArr consumed only after the first staging __syncthreads()

    floatx4 acc[4];
    #pragma unroll
    for (int j = 0; j < 4; j++)
        acc[j] = (floatx4){0.0f, 0.0f, 0.0f, 0.0f};

    int gr = rowW + l15;
    if (gr > M - 1) gr = M - 1;

    bool firstChunk = true;

    for (int s = 0; s < 2; s++) {
        const void*     A     = s ? A2  : A1;
        const ushort_t* Wt    = s ? Wt2 : Wt1;
        const int       K     = s ? K2  : K1;
        const int       atype = s ? 1   : a1type;
        const int       doAf  = (affineSeg == s);
        if (A == nullptr) continue;

        for (int kc = 0; kc < K; kc += 128) {
            if (!firstChunk) __syncthreads();   // protect Bs until prior compute done
            firstChunk = false;

            // ---- stage B panel: 128 rows x 128 K bf16 (32 KB), 4 uint4/thread ----
            #pragma unroll
            for (int p = 0; p < 4; p++) {
                const int idx = p * 512 + t;    // 0..2047
                const int n   = idx >> 4;
                const int c0  = (idx & 15) * 8;
                *(uint4*)(Bs + n * 136 + c0) =
                    *(const uint4*)(Wt + (size_t)n * K + kc + c0);
            }
            __syncthreads();

            // ---- A fragments: 4 k-steps, per-lane, direct global->VGPR ----
            short8 afrag[4];
            if (atype == 1) {
                const ushort_t* Ab = (const ushort_t*)A;
                const size_t base = (size_t)gr * K + kc + ksq;
                #pragma unroll
                for (int ks = 0; ks < 4; ks++)
                    afrag[ks] = *(const short8*)(Ab + base + ks * 32);
                if (doAf) {
                    #pragma unroll
                    for (int ks = 0; ks < 4; ks++) {
                        const int k0 = ks * 32 + ksq;   // K==128 when affine
                        uint4 u = __builtin_bit_cast(uint4, afrag[ks]);
                        uint4 w;
                        unsigned int* up = (unsigned int*)&u;
                        unsigned int* wp = (unsigned int*)&w;
                        #pragma unroll
                        for (int h = 0; h < 4; h++) {
                            float lo = aArr[k0 + h * 2]     * bf2f(up[h] & 0xffffu) + bArr[k0 + h * 2];
                            float hi = aArr[k0 + h * 2 + 1] * bf2f(up[h] >> 16)     + bArr[k0 + h * 2 + 1];
                            if (affineRelu) { lo = fmaxf(lo, 0.0f); hi = fmaxf(hi, 0.0f); }
                            wp[h] = pack2(lo, hi);
                        }
                        afrag[ks] = __builtin_bit_cast(short8, w);
                    }
                }
            } else {
                const float* Af = (const float*)A;
                const size_t base = (size_t)gr * K + kc + ksq;
                #pragma unroll
                for (int ks = 0; ks < 4; ks++) {
                    float4 v0 = *(const float4*)(Af + base + ks * 32);
                    float4 v1 = *(const float4*)(Af + base + ks * 32 + 4);
                    if (doAf) {
                        const int k0 = ks * 32 + ksq;
                        const float4 sa0 = *(const float4*)(aArr + k0);
                        const float4 sb0 = *(const float4*)(bArr + k0);
                        const float4 sa1 = *(const float4*)(aArr + k0 + 4);
                        const float4 sb1 = *(const float4*)(bArr + k0 + 4);
                        v0.x = sa0.x * v0.x + sb0.x;
                        v0.y = sa0.y * v0.y + sb0.y;
                        v0.z = sa0.z * v0.z + sb0.z;
                        v0.w = sa0.w * v0.w + sb0.w;
                        v1.x = sa1.x * v1.x + sb1.x;
                        v1.y = sa1.y * v1.y + sb1.y;
                        v1.z = sa1.z * v1.z + sb1.z;
                        v1.w = sa1.w * v1.w + sb1.w;
                        if (affineRelu) {
                            v0.x = fmaxf(v0.x, 0.0f); v0.y = fmaxf(v0.y, 0.0f);
                            v0.z = fmaxf(v0.z, 0.0f); v0.w = fmaxf(v0.w, 0.0f);
                            v1.x = fmaxf(v1.x, 0.0f); v1.y = fmaxf(v1.y, 0.0f);
                            v1.z = fmaxf(v1.z, 0.0f); v1.w = fmaxf(v1.w, 0.0f);
                        }
                    }
                    uint4 w;
                    w.x = pack2(v0.x, v0.y);
                    w.y = pack2(v0.z, v0.w);
                    w.z = pack2(v1.x, v1.y);
                    w.w = pack2(v1.z, v1.w);
                    afrag[ks] = __builtin_bit_cast(short8, w);
                }
            }

            // ---- compute: wave's 64 cols (nh half), ks outer ----
            #pragma unroll
            for (int ks = 0; ks < 4; ks++) {
                const int ko = ks * 32 + ksq;
                short8 b[4];
                #pragma unroll
                for (int j = 0; j < 4; j++)
                    b[j] = *(const short8*)(Bs + (nh * 64 + j * 16 + l15) * 136 + ko);
                #pragma unroll
                for (int j = 0; j < 4; j++)
                    acc[j] = __builtin_amdgcn_mfma_f32_16x16x32_bf16(
                        afrag[ks], b[j], acc[j], 0, 0, 0);
            }
        }
    }

    // ---- epilogue: bias, C store (fp32 and/or bf16), per-column stats ----
    float s_[4], q_[4];
    #pragma unroll
    for (int j = 0; j < 4; j++) { s_[j] = 0.0f; q_[j] = 0.0f; }

    #pragma unroll
    for (int j = 0; j < 4; j++) {
        const int col = nh * 64 + j * 16 + l15;
        const float bv = bias[col];
        const int rbase = rowW + quad * 4;
        #pragma unroll
        for (int reg = 0; reg < 4; reg++) {
            const float val = acc[j][reg] + bv;
            const int r_ = rbase + reg;
            if (r_ < M) {
                if (Cf) Cf[(size_t)r_ * HIDC + col] = val;
                if (Cb) Cb[(size_t)r_ * HIDC + col] = f2bf(val);
                s_[j] += val;
                q_[j] += val * val;
            }
        }
    }
    #pragma unroll
    for (int j = 0; j < 4; j++) {
        s_[j] += __shfl_xor(s_[j], 16, 64);
        s_[j] += __shfl_xor(s_[j], 32, 64);
        q_[j] += __shfl_xor(q_[j], 16, 64);
        q_[j] += __shfl_xor(q_[j], 32, 64);
    }
    if (quad == 0) {
        #pragma unroll
        for (int j = 0; j < 4; j++) {
            red_s[mt][nh * 64 + j * 16 + l15] = s_[j];
            red_q[mt][nh * 64 + j * 16 + l15] = q_[j];
        }
    }
    __syncthreads();
    if (t < 128) {
        const float S = red_s[0][t] + red_s[1][t] + red_s[2][t] + red_s[3][t];
        const float Q = red_q[0][t] + red_q[1][t] + red_q[2][t] + red_q[3][t];
        float* slot = outStats + (blockIdx.x & (NSLOT - 1)) * 256;
        atomicAdd(&slot[t], S);
        atomicAdd(&slot[128 + t], Q);
    }
}

// ---------------------------------------------------------------------------
// BN apply: dst fp32 (optional) and/or dst bf16 (optional), + optional relu.
// stats is NSLOT-slotted.
// ---------------------------------------------------------------------------
__global__ __launch_bounds__(256) void bn_apply_kernel(
    const float* __restrict__ src, float* __restrict__ dstF,
    ushort_t* __restrict__ dstB, const float* __restrict__ stats,
    const float* __restrict__ gamma, const float* __restrict__ beta,
    int relu, int M)
{
    __shared__ float sc[128], sh[128];
    const int t = threadIdx.x;
    if (t < 128) {
        float sS = 0.0f, sQ = 0.0f;
        #pragma unroll
        for (int s8 = 0; s8 < NSLOT; s8++) {
            sS += stats[s8 * 256 + t];
            sQ += stats[s8 * 256 + 128 + t];
        }
        const float invM = 1.0f / (float)M;
        const float mean = sS * invM;
        float var = sQ * invM - mean * mean;
        if (var < 0.0f) var = 0.0f;
        const float s = gamma[t] / sqrtf(var + EPSC);
        sc[t] = s;
        sh[t] = beta[t] - mean * s;
    }
    __syncthreads();

    const int total4 = M * HIDC / 4;
    for (int i = blockIdx.x * 256 + t; i < total4; i += gridDim.x * 256) {
        float4 v = ((const float4*)src)[i];
        const int c = (i * 4) & 127;
        v.x = v.x * sc[c]     + sh[c];
        v.y = v.y * sc[c + 1] + sh[c + 1];
        v.z = v.z * sc[c + 2] + sh[c + 2];
        v.w = v.w * sc[c + 3] + sh[c + 3];
        if (relu) {
            v.x = fmaxf(v.x, 0.0f); v.y = fmaxf(v.y, 0.0f);
            v.z = fmaxf(v.z, 0.0f); v.w = fmaxf(v.w, 0.0f);
        }
        if (dstF) ((float4*)dstF)[i] = v;
        if (dstB) {
            uint2 w;
            w.x = pack2(v.x, v.y);
            w.y = pack2(v.z, v.w);
            *(uint2*)(dstB + (size_t)i * 4) = w;
        }
    }
}

// ---------------------------------------------------------------------------
// CSR build — atomic-free two-level counting sort. Edges packed 32-bit
// (src<<16 | dst). Fine phase orders by (dst&255, srctile). col is INT.
// ---------------------------------------------------------------------------
__global__ __launch_bounds__(256) void bucket_hist_kernel(
    const int* __restrict__ dstArr, int* __restrict__ hist2D)
{
    __shared__ int hist[NB];
    const int t = threadIdx.x;
    for (int i = t; i < NB; i += 256) hist[i] = 0;
    __syncthreads();
    const int e0 = blockIdx.x * CHUNK;
    const int e1 = e0 + CHUNK;   // EE = GA*CHUNK exactly
    for (int e = e0 + t; e < e1; e += 256)
        atomicAdd(&hist[dstArr[e] >> 8], 1);
    __syncthreads();
    for (int i = t; i < NB; i += 256)
        hist2D[(size_t)i * GA + blockIdx.x] = hist[i];
}

// per-bucket exclusive scan over the GA=512 phase-A block counts.
__global__ __launch_bounds__(256) void bucket_scan_kernel(
    int* __restrict__ hist2D, int* __restrict__ rowTot)
{
    __shared__ int wtot[4];
    const int b = blockIdx.x;
    const int t = threadIdx.x;
    int* row = hist2D + (size_t)b * GA;
    const int v0 = row[2 * t];
    const int v1 = row[2 * t + 1];
    const int pair = v0 + v1;
    const int lane = t & 63, w = t >> 6;
    int x = pair;
    #pragma unroll
    for (int off = 1; off < 64; off <<= 1) {
        const int y = __shfl_up(x, off);
        if (lane >= off) x += y;
    }
    if (lane == 63) wtot[w] = x;
    __syncthreads();
    int woff = 0;
    #pragma unroll
    for (int j = 0; j < 4; j++) if (j < w) woff += wtot[j];
    const int excl = x + woff - pair;
    row[2 * t]     = excl;
    row[2 * t + 1] = excl + v0;
    if (t == 255) rowTot[b] = excl + pair;
}

// 1 block: exclusive scan of NB bucket totals -> bucketBase.
__global__ __launch_bounds__(256) void bucket_base_kernel(
    const int* __restrict__ rowTot, int* __restrict__ bucketBase,
    int* __restrict__ rowp)
{
    __shared__ int wtot[4];
    const int t = threadIdx.x;
    const int tot = (t < NB) ? rowTot[t] : 0;
    const int lane = t & 63, w = t >> 6;
    int x = tot;
    #pragma unroll
    for (int off = 1; off < 64; off <<= 1) {
        const int y = __shfl_up(x, off);
        if (lane >= off) x += y;
    }
    if (lane == 63) wtot[w] = x;
    __syncthreads();
    int woff = 0;
    #pragma unroll
    for (int j = 0; j < 4; j++) if (j < w) woff += wtot[j];
    const int excl = x + woff - tot;
    if (t < NB) bucketBase[t] = excl;
    if (t == 0) { bucketBase[NB] = EE; rowp[NN] = EE; }
}

__global__ __launch_bounds__(256) void bucket_scatter_kernel(
    const int* __restrict__ srcArr, const int* __restrict__ dstArr,
    const int* __restrict__ hist2D, const int* __restrict__ bucketBase,
    unsigned int* __restrict__ ebuf)
{
    __shared__ int cur[NB];
    const int t = threadIdx.x;
    for (int i = t; i < NB; i += 256)
        cur[i] = bucketBase[i] + hist2D[(size_t)i * GA + blockIdx.x];
    __syncthreads();
    const int e0 = blockIdx.x * CHUNK;
    const int e1 = e0 + CHUNK;
    for (int e = e0 + t; e < e1; e += 256) {
        const int d = dstArr[e];
        const int s = srcArr[e];
        const int p = atomicAdd(&cur[d >> 8], 1);
        ebuf[p] = ((unsigned int)s << 16) | (unsigned int)d;
    }
}

__global__ __launch_bounds__(256) void fine_sort_kernel(
    const unsigned int* __restrict__ ebuf, const int* __restrict__ bucketBase,
    int* __restrict__ rowp, int* __restrict__ col)
{
    __shared__ int cnt[NKEY];       // 8 KB: (dst&255)<<3 | srctile
    __shared__ int wtot[4];
    const int b = blockIdx.x;
    const int t = threadIdx.x;
    const int bb0 = bucketBase[b];
    const int bb1 = bucketBase[b + 1];
    #pragma unroll
    for (int i = 0; i < 8; i++) cnt[t * 8 + i] = 0;
    __syncthreads();
    for (int e = bb0 + t; e < bb1; e += 256) {
        const unsigned int sd = ebuf[e];
        const int key = (int)((sd & 255u) << 3) | (int)(sd >> (16 + STILE_SHIFT));
        atomicAdd(&cnt[key], 1);
    }
    __syncthreads();
    int loc[8];
    int tot = 0;
    #pragma unroll
    for (int i = 0; i < 8; i++) { loc[i] = tot; tot += cnt[t * 8 + i]; }
    const int lane = t & 63, w = t >> 6;
    int x = tot;
    #pragma unroll
    for (int off = 1; off < 64; off <<= 1) {
        const int y = __shfl_up(x, off);
        if (lane >= off) x += y;
    }
    if (lane == 63) wtot[w] = x;
    __syncthreads();
    int woff = 0;
    #pragma unroll
    for (int j = 0; j < 4; j++) if (j < w) woff += wtot[j];
    const int excl = x + woff - tot;
    const int node = b * 256 + t;
    if (node < NN) rowp[node] = bb0 + excl;
    __syncthreads();
    #pragma unroll
    for (int i = 0; i < 8; i++) cnt[t * 8 + i] = excl + loc[i];  // cursors
    __syncthreads();
    for (int e = bb0 + t; e < bb1; e += 256) {
        const unsigned int sd = ebuf[e];
        const int key = (int)((sd & 255u) << 3) | (int)(sd >> (16 + STILE_SHIFT));
        const int p = atomicAdd(&cnt[key], 1);
        col[bb0 + p] = (int)(sd >> 16);
    }
}

// ---------------------------------------------------------------------------
// Mean aggregation (plain): one wave per node, 2 cols/lane, grid-stride over
// 16384 waves. col is INT so wave-uniform col[j+i] loads compile to scalar
// s_load broadcasts (measured: ushort col costs +7-10us/launch).
// ---------------------------------------------------------------------------
__global__ __launch_bounds__(256) void agg_kernel(
    const ushort_t* __restrict__ F, const int* __restrict__ row_ptr,
    const int* __restrict__ col, ushort_t* __restrict__ Mout)
{
    const int lane = threadIdx.x & 63;
    const int wave = blockIdx.x * 4 + (threadIdx.x >> 6);
    const int nwaves = gridDim.x * 4;
    const int coff = lane * 2;

    for (int n = wave; n < NN; n += nwaves) {
        const int b = __builtin_amdgcn_readfirstlane(row_ptr[n]);
        const int e = __builtin_amdgcn_readfirstlane(row_ptr[n + 1]);
        const int deg = e - b;
        float accx = 0.0f, accy = 0.0f;
        int j = b;
        for (; j + 8 <= e; j += 8) {
            const int s0 = col[j + 0];
            const int s1 = col[j + 1];
            const int s2 = col[j + 2];
            const int s3 = col[j + 3];
            const int s4 = col[j + 4];
            const int s5 = col[j + 5];
            const int s6 = col[j + 6];
            const int s7 = col[j + 7];
            const unsigned int v0 = *(const unsigned int*)(F + (size_t)s0 * HIDC + coff);
            const unsigned int v1 = *(const unsigned int*)(F + (size_t)s1 * HIDC + coff);
            const unsigned int v2 = *(const unsigned int*)(F + (size_t)s2 * HIDC + coff);
            const unsigned int v3 = *(const unsigned int*)(F + (size_t)s3 * HIDC + coff);
            const unsigned int v4 = *(const unsigned int*)(F + (size_t)s4 * HIDC + coff);
            const unsigned int v5 = *(const unsigned int*)(F + (size_t)s5 * HIDC + coff);
            const unsigned int v6 = *(const unsigned int*)(F + (size_t)s6 * HIDC + coff);
            const unsigned int v7 = *(const unsigned int*)(F + (size_t)s7 * HIDC + coff);
            accx += bf2f(v0 & 0xffffu) + bf2f(v1 & 0xffffu) + bf2f(v2 & 0xffffu)
                  + bf2f(v3 & 0xffffu) + bf2f(v4 & 0xffffu) + bf2f(v5 & 0xffffu)
                  + bf2f(v6 & 0xffffu) + bf2f(v7 & 0xffffu);
            accy += bf2f(v0 >> 16) + bf2f(v1 >> 16) + bf2f(v2 >> 16)
                  + bf2f(v3 >> 16) + bf2f(v4 >> 16) + bf2f(v5 >> 16)
                  + bf2f(v6 >> 16) + bf2f(v7 >> 16);
        }
        for (; j < e; j++) {
            const unsigned int v = *(const unsigned int*)(F + (size_t)col[j] * HIDC + coff);
            accx += bf2f(v & 0xffffu);
            accy += bf2f(v >> 16);
        }
        const float inv = 1.0f / (float)(deg > 1 ? deg : 1);
        *(unsigned int*)(Mout + (size_t)n * HIDC + coff) =
            pack2(accx * inv, accy * inv);
    }
}

// ---------------------------------------------------------------------------
// Mean aggregation + BN affine on the MEAN (affine commutes; deg==0 -> 0).
// stats is NSLOT-slotted. Separate kernel so the plain pass stays lean.
// ---------------------------------------------------------------------------
__global__ __launch_bounds__(256) void agg_bn_kernel(
    const ushort_t* __restrict__ F, const int* __restrict__ row_ptr,
    const int* __restrict__ col, ushort_t* __restrict__ Mout,
    const float* __restrict__ preStats, const float* __restrict__ preG,
    const float* __restrict__ preBe)
{
    const int lane = threadIdx.x & 63;
    const int wave = blockIdx.x * 4 + (threadIdx.x >> 6);
    const int nwaves = gridDim.x * 4;
    const int coff = lane * 2;

    float s0 = 0.0f, s1 = 0.0f, q0 = 0.0f, q1 = 0.0f;
    #pragma unroll
    for (int s8 = 0; s8 < NSLOT; s8++) {
        s0 += preStats[s8 * 256 + coff];
        s1 += preStats[s8 * 256 + coff + 1];
        q0 += preStats[s8 * 256 + 128 + coff];
        q1 += preStats[s8 * 256 + 128 + coff + 1];
    }
    const float invM = 1.0f / (float)NN;
    const float m0 = s0 * invM;
    const float m1 = s1 * invM;
    float v0_ = q0 * invM - m0 * m0;
    float v1_ = q1 * invM - m1 * m1;
    if (v0_ < 0.0f) v0_ = 0.0f;
    if (v1_ < 0.0f) v1_ = 0.0f;
    const float sc0 = preG[coff] / sqrtf(v0_ + EPSC);
    const float sc1 = preG[coff + 1] / sqrtf(v1_ + EPSC);
    const float sh0 = preBe[coff] - m0 * sc0;
    const float sh1 = preBe[coff + 1] - m1 * sc1;

    for (int n = wave; n < NN; n += nwaves) {
        const int b = __builtin_amdgcn_readfirstlane(row_ptr[n]);
        const int e = __builtin_amdgcn_readfirstlane(row_ptr[n + 1]);
        const int deg = e - b;
        float accx = 0.0f, accy = 0.0f;
        int j = b;
        for (; j + 8 <= e; j += 8) {
            const int s0_ = col[j + 0];
            const int s1_ = col[j + 1];
            const int s2_ = col[j + 2];
            const int s3_ = col[j + 3];
            const int s4_ = col[j + 4];
            const int s5_ = col[j + 5];
            const int s6_ = col[j + 6];
            const int s7_ = col[j + 7];
            const unsigned int v0 = *(const unsigned int*)(F + (size_t)s0_ * HIDC + coff);
            const unsigned int v1 = *(const unsigned int*)(F + (size_t)s1_ * HIDC + coff);
            const unsigned int v2 = *(const unsigned int*)(F + (size_t)s2_ * HIDC + coff);
            const unsigned int v3 = *(const unsigned int*)(F + (size_t)s3_ * HIDC + coff);
            const unsigned int v4 = *(const unsigned int*)(F + (size_t)s4_ * HIDC + coff);
            const unsigned int v5 = *(const unsigned int*)(F + (size_t)s5_ * HIDC + coff);
            const unsigned int v6 = *(const unsigned int*)(F + (size_t)s6_ * HIDC + coff);
            const unsigned int v7 = *(const unsigned int*)(F + (size_t)s7_ * HIDC + coff);
            accx += bf2f(v0 & 0xffffu) + bf2f(v1 & 0xffffu) + bf2f(v2 & 0xffffu)
                  + bf2f(v3 & 0xffffu) + bf2f(v4 & 0xffffu) + bf2f(v5 & 0xffffu)
                  + bf2f(v6 & 0xffffu) + bf2f(v7 & 0xffffu);
            accy += bf2f(v0 >> 16) + bf2f(v1 >> 16) + bf2f(v2 >> 16)
                  + bf2f(v3 >> 16) + bf2f(v4 >> 16) + bf2f(v5 >> 16)
                  + bf2f(v6 >> 16) + bf2f(v7 >> 16);
        }
        for (; j < e; j++) {
            const unsigned int v = *(const unsigned int*)(F + (size_t)col[j] * HIDC + coff);
            accx += bf2f(v & 0xffffu);
            accy += bf2f(v >> 16);
        }
        float ox, oy;
        if (deg == 0) {
            ox = 0.0f; oy = 0.0f;
        } else {
            const float inv = 1.0f / (float)deg;
            ox = accx * inv * sc0 + sh0;
            oy = accy * inv * sc1 + sh1;
        }
        *(unsigned int*)(Mout + (size_t)n * HIDC + coff) = pack2(ox, oy);
    }
}

// ---------------------------------------------------------------------------
extern "C" void kernel_launch(void* const* d_in, const int* in_sizes, int n_in,
                              void* d_out, int out_size, void* d_ws, size_t ws_size,
                              hipStream_t stream)
{
    const float* x     = (const float*)d_in[0];
    const int*   ei    = (const int*)  d_in[1];
    const float* W_in  = (const float*)d_in[2];
    const float* b_in  = (const float*)d_in[3];
    const float* g1    = (const float*)d_in[4];
    const float* be1   = (const float*)d_in[5];
    const float* W_hid = (const float*)d_in[6];
    const float* b_hid = (const float*)d_in[7];
    const float* g2    = (const float*)d_in[8];
    const float* be2   = (const float*)d_in[9];
    const float* Wl1   = (const float*)d_in[10];
    const float* bl1   = (const float*)d_in[11];
    const float* Wr1   = (const float*)d_in[12];
    const float* g3    = (const float*)d_in[13];
    const float* be3   = (const float*)d_in[14];
    const float* Wl2   = (const float*)d_in[15];
    const float* bl2   = (const float*)d_in[16];
    const float* Wr2   = (const float*)d_in[17];
    const float* g4    = (const float*)d_in[18];
    const float* be4   = (const float*)d_in[19];

    const int* srcArr = ei;        // edge_index[0]
    const int* dstArr = ei + EE;   // edge_index[1]

    char* ws = (char*)d_ws;
    float*    bufA      = (float*)ws;    ws += (size_t)NN * HIDC * sizeof(float);
    float*    bufB      = (float*)ws;    ws += (size_t)NN * HIDC * sizeof(float);
    ushort_t* featB16   = (ushort_t*)ws; ws += (size_t)NN * HIDC * sizeof(ushort_t);
    ushort_t* o3B16     = (ushort_t*)ws; ws += (size_t)NN * HIDC * sizeof(ushort_t);
    ushort_t* aggB16    = (ushort_t*)ws; ws += (size_t)NN * HIDC * sizeof(ushort_t);
    float*    stats     = (float*)ws;    ws += 4 * STATS_STRIDE * sizeof(float);
    int*      hist2D    = (int*)ws;      ws += (size_t)NB * GA * sizeof(int);
    int*      rowTot    = (int*)ws;      ws += (NB + 4) * sizeof(int);
    int*      bucketBase= (int*)ws;      ws += (NB + 4) * sizeof(int);
    int*      rowp      = (int*)ws;      ws += (size_t)(NN + 4) * sizeof(int);
    int*      colIdx    = (int*)ws;      ws += (size_t)EE * sizeof(int);
    unsigned int* ebuf  = (unsigned int*)ws; ws += (size_t)EE * sizeof(unsigned int);
    ushort_t* Wt_in     = (ushort_t*)ws; ws += 128 * 256 * sizeof(ushort_t);
    ushort_t* Wt_hid    = (ushort_t*)ws; ws += 128 * 128 * sizeof(ushort_t);
    ushort_t* Wtl1      = (ushort_t*)ws; ws += 128 * 128 * sizeof(ushort_t);
    ushort_t* Wtr1      = (ushort_t*)ws; ws += 128 * 128 * sizeof(ushort_t);
    ushort_t* Wtl2      = (ushort_t*)ws; ws += 128 * 128 * sizeof(ushort_t);
    ushort_t* Wtr2      = (ushort_t*)ws; ws += 128 * 128 * sizeof(ushort_t);

    float* out0 = (float*)d_out;             // feat  [NN*HID] fp32
    float* out1 = out0 + (size_t)NN * HIDC;  // out   [NN*HID] fp32

    // zero: stats only (counting sort is store-based, nothing else needs init)
    hipMemsetAsync(stats, 0, 4 * STATS_STRIDE * sizeof(float), stream);

    // weight transpose + bf16 convert (one launch, 448 blocks)
    tcvt_all_kernel<<<448, 256, 0, stream>>>(W_in, W_hid, Wl1, Wr1, Wl2, Wr2,
                                             Wt_in, Wt_hid, Wtl1, Wtr1, Wtl2, Wtr2);

    // CSR build — atomic-free counting sort (packed edges, int col)
    bucket_hist_kernel<<<GA, 256, 0, stream>>>(dstArr, hist2D);
    bucket_scan_kernel<<<NB, 256, 0, stream>>>(hist2D, rowTot);
    bucket_base_kernel<<<1, 256, 0, stream>>>(rowTot, bucketBase, rowp);
    bucket_scatter_kernel<<<GA, 256, 0, stream>>>(srcArr, dstArr, hist2D,
                                                  bucketBase, ebuf);
    fine_sort_kernel<<<NB, 256, 0, stream>>>(ebuf, bucketBase, rowp, colIdx);

    const int gemmGrid = (NN + 63) / 64;   // 782 blocks x 512 threads

    // stage 1: input linear (x fp32, K=256) -> bufA fp32 + stats0
    mfma_gemm_kernel<<<gemmGrid, 512, 0, stream>>>(
        x, Wt_in, IN_DIMC, 0, nullptr, nullptr, 0,
        b_in, bufA, nullptr, NN, -1, 0, nullptr, nullptr, nullptr,
        stats + 0 * STATS_STRIDE);

    // stage 2: hidden linear, BN1+relu fused on A-load -> bufB fp32 + stats1
    mfma_gemm_kernel<<<gemmGrid, 512, 0, stream>>>(
        bufA, Wt_hid, HIDC, 0, nullptr, nullptr, 0,
        b_hid, bufB, nullptr, NN, 0, 1, stats + 0 * STATS_STRIDE, g1, be1,
        stats + 1 * STATS_STRIDE);

    // BN2+relu -> out0 (fp32) + featB16 (bf16)
    bn_apply_kernel<<<1024, 256, 0, stream>>>(bufB, out0, featB16,
                                              stats + 1 * STATS_STRIDE, g2, be2, 1, NN);

    // stage 3: SAGE1 -> o3B16 RAW bf16 (BN3 deferred: affine commutes w/ mean)
    agg_kernel<<<4096, 256, 0, stream>>>(featB16, rowp, colIdx, aggB16);
    mfma_gemm_kernel<<<gemmGrid, 512, 0, stream>>>(
        aggB16, Wtl1, HIDC, 1, featB16, Wtr1, HIDC,
        bl1, nullptr, o3B16, NN, -1, 0, nullptr, nullptr, nullptr,
        stats + 2 * STATS_STRIDE);

    // stage 4: SAGE2 — agg applies BN3 to the mean; GEMM applies BN3 on A2
    agg_bn_kernel<<<4096, 256, 0, stream>>>(o3B16, rowp, colIdx, aggB16,
                                            stats + 2 * STATS_STRIDE, g3, be3);
    mfma_gemm_kernel<<<gemmGrid, 512, 0, stream>>>(
        aggB16, Wtl2, HIDC, 1, o3B16, Wtr2, HIDC,
        bl2, bufB, nullptr, NN, 1, 0, stats + 2 * STATS_STRIDE, g3, be3,
        stats + 3 * STATS_STRIDE);

    // BN4 -> out1 (fp32)
    bn_apply_kernel<<<1024, 256, 0, stream>>>(bufB, out1, nullptr,
                                              stats + 3 * STATS_STRIDE, g4, be4, 0, NN);
}